// Round 2
// baseline (693.295 us; speedup 1.0000x reference)
//
#include <hip/hip_runtime.h>
#include <math.h>

#define NND 20000
#define DIM 512
#define NE  320000

typedef __attribute__((ext_vector_type(8))) short short8;
typedef __attribute__((ext_vector_type(4))) short short4v;
typedef __attribute__((ext_vector_type(4))) float floatx4;

__device__ inline float bf2f(unsigned short h) {
    unsigned int u = ((unsigned int)h) << 16;
    return __uint_as_float(u);
}
__device__ inline unsigned short f2bf(float f) {
    unsigned int u = __float_as_uint(f);
    unsigned int r = (u + 0x7fffu + ((u >> 16) & 1u)) >> 16;
    return (unsigned short)r;
}

// ---------------- fp32 -> bf16 matrix conversion (for W matrices) -------------
__global__ __launch_bounds__(256) void k_cvt(const float* __restrict__ in,
                                             unsigned short* __restrict__ out,
                                             int n4) {
    int i = blockIdx.x * 256 + threadIdx.x;
    if (i >= n4) return;
    floatx4 f = *(const floatx4*)(in + (size_t)i * 4);
    union { short4v v; unsigned short u[4]; } o;
#pragma unroll
    for (int j = 0; j < 4; j++) o.u[j] = f2bf(f[j]);
    *(short4v*)(out + (size_t)i * 4) = o.v;
}

// ---------------- logmap0: t = atanh(||x||)/||x|| * x  (fp32 in, bf16 out) ----
__global__ __launch_bounds__(64) void k_logmap(const float* __restrict__ x,
                                               unsigned short* __restrict__ t) {
    int row = blockIdx.x;
    int lane = threadIdx.x;
    const floatx4* xp = (const floatx4*)(x + (size_t)row * DIM + lane * 8);
    floatx4 x0 = xp[0], x1 = xp[1];
    float ss = 0.f;
#pragma unroll
    for (int i = 0; i < 4; i++) { ss += x0[i] * x0[i]; ss += x1[i] * x1[i]; }
#pragma unroll
    for (int off = 32; off >= 1; off >>= 1) ss += __shfl_xor(ss, off, 64);
    float n  = sqrtf(ss);
    float nc = fminf(fmaxf(n, 1e-7f), 1.0f - 1e-6f);
    float fac = atanhf(nc) / nc;
    union { short8 v; unsigned short u[8]; } o;
#pragma unroll
    for (int i = 0; i < 4; i++) { o.u[i] = f2bf(fac * x0[i]); o.u[4 + i] = f2bf(fac * x1[i]); }
    *(short8*)(t + (size_t)row * DIM + lane * 8) = o.v;
}

// ---------------- GEMM: out = (A @ W^T + bias) * scale  -----------------------
// A: [M x 512] bf16 row-major, W: [512 x 512] bf16 row-major (out = dot(A_row, W_row))
// wave computes 16(M) x 64(N); mfma_f32_16x16x32_bf16; writes bf16 or fp32.
__global__ __launch_bounds__(256) void k_gemm(const unsigned short* __restrict__ A,
                                              const unsigned short* __restrict__ W,
                                              const float* __restrict__ bias,
                                              unsigned short* __restrict__ out_bf,
                                              float* __restrict__ out_f,
                                              float scale, int M) {
    int wave = threadIdx.x >> 6, lane = threadIdx.x & 63;
    int wid = blockIdx.x * 4 + wave;
    int mt = wid >> 3, nt = wid & 7;          // 8 n-tiles of 64 across DIM=512
    int m0 = mt * 16, n0 = nt * 64;
    if (m0 >= M) return;
    int lr = lane & 15, qd = lane >> 4;
    floatx4 acc[4] = {{0,0,0,0},{0,0,0,0},{0,0,0,0},{0,0,0,0}};
    const unsigned short* ap = A + (size_t)(m0 + lr) * DIM + qd * 8;
    const unsigned short* wp = W + (size_t)(n0 + lr) * DIM + qd * 8;
    for (int kb = 0; kb < DIM; kb += 32) {
        short8 a = *(const short8*)(ap + kb);
#pragma unroll
        for (int j = 0; j < 4; j++) {
            short8 b = *(const short8*)(wp + (size_t)j * 16 * DIM + kb);
            acc[j] = __builtin_amdgcn_mfma_f32_16x16x32_bf16(a, b, acc[j], 0, 0, 0);
        }
    }
    int row0 = m0 + qd * 4, col = lr;
#pragma unroll
    for (int j = 0; j < 4; j++) {
        int n = n0 + j * 16 + col;
        float bv = bias[n];
#pragma unroll
        for (int r = 0; r < 4; r++) {
            float val = (acc[j][r] + bv) * scale;
            size_t idx = (size_t)(row0 + r) * DIM + n;
            if (out_bf) out_bf[idx] = f2bf(val);
            else        out_f[idx]  = val;
        }
    }
}

// ---------------- edge scores: es[e] = exp(dot(q[dst], k[src])) ---------------
__global__ __launch_bounds__(256) void k_score(const unsigned short* __restrict__ q,
                                               const unsigned short* __restrict__ k,
                                               const int* __restrict__ src,
                                               const int* __restrict__ dst,
                                               float* __restrict__ es) {
    int gt = blockIdx.x * 256 + threadIdx.x;
    int e = gt >> 6, lane = gt & 63;
    if (e >= NE) return;
    int s = src[e], d = dst[e];
    short8 qa = *(const short8*)(q + (size_t)d * DIM + lane * 8);
    short8 ka = *(const short8*)(k + (size_t)s * DIM + lane * 8);
    float sum = 0.f;
#pragma unroll
    for (int i = 0; i < 8; i++) sum += bf2f((unsigned short)qa[i]) * bf2f((unsigned short)ka[i]);
#pragma unroll
    for (int off = 32; off >= 1; off >>= 1) sum += __shfl_xor(sum, off, 64);
    if (lane == 0) es[e] = expf(sum);
}

// ---------------- CSR build ---------------------------------------------------
__global__ void k_hist(const int* __restrict__ dst, int* __restrict__ counts) {
    int e = blockIdx.x * 256 + threadIdx.x;
    if (e < NE) atomicAdd(&counts[dst[e]], 1);
}

__global__ __launch_bounds__(1024) void k_scan(const int* __restrict__ counts,
                                               int* __restrict__ offsets,
                                               int* __restrict__ pos) {
    const int C = 20;  // 1024*20 = 20480 >= 20000
    __shared__ int wsum[16];
    __shared__ int wpre[16];
    int tid = threadIdx.x, lane = tid & 63, w = tid >> 6;
    int local[C];
    int run = 0;
#pragma unroll
    for (int i = 0; i < C; i++) {
        int idx = tid * C + i;
        int c = (idx < NND) ? counts[idx] : 0;
        local[i] = run; run += c;
    }
    int v = run;
#pragma unroll
    for (int off = 1; off < 64; off <<= 1) {
        int u = __shfl_up(v, off, 64);
        if (lane >= off) v += u;
    }
    if (lane == 63) wsum[w] = v;
    __syncthreads();
    if (tid == 0) { int acc = 0; for (int i = 0; i < 16; i++) { wpre[i] = acc; acc += wsum[i]; } }
    __syncthreads();
    int texcl = wpre[w] + (v - run);
#pragma unroll
    for (int i = 0; i < C; i++) {
        int idx = tid * C + i;
        if (idx < NND) { int o = texcl + local[i]; offsets[idx] = o; pos[idx] = o; }
    }
    if (tid == 1023) offsets[NND] = texcl + run;
}

__global__ void k_scatter(const int* __restrict__ dst, int* __restrict__ pos,
                          int* __restrict__ sorted) {
    int e = blockIdx.x * 256 + threadIdx.x;
    if (e < NE) { int p = atomicAdd(&pos[dst[e]], 1); sorted[p] = e; }
}

// ---------------- per-node softmax-weighted aggregation -----------------------
// attn[n] = sum_e (es[e]/denom) * v[src[e]]   over e with dst==n
__global__ __launch_bounds__(256) void k_agg(const int* __restrict__ offsets,
                                             const int* __restrict__ sorted,
                                             const int* __restrict__ src,
                                             const float* __restrict__ es,
                                             const unsigned short* __restrict__ v,
                                             unsigned short* __restrict__ attn) {
    int nnode = blockIdx.x, tid = threadIdx.x, lane = tid & 63, w = tid >> 6;
    int beg = offsets[nnode], end = offsets[nnode + 1];
    __shared__ float red[4];
    __shared__ float ws[64];
    __shared__ int   ss[64];
    float dsum = 0.f;
    for (int i = beg + tid; i < end; i += 256) dsum += es[sorted[i]];
#pragma unroll
    for (int off = 32; off >= 1; off >>= 1) dsum += __shfl_xor(dsum, off, 64);
    if (lane == 0) red[w] = dsum;
    __syncthreads();
    float denom = red[0] + red[1] + red[2] + red[3];
    float inv = 1.0f / denom;
    float a0 = 0.f, a1 = 0.f;
    for (int chunk = beg; chunk < end; chunk += 64) {
        int cnt = min(64, end - chunk);
        __syncthreads();
        if (tid < cnt) { int e = sorted[chunk + tid]; ws[tid] = es[e]; ss[tid] = src[e]; }
        __syncthreads();
        for (int i = 0; i < cnt; i++) {
            unsigned int pv = *(const unsigned int*)(v + (size_t)ss[i] * DIM + tid * 2);
            float wgt = ws[i];
            a0 += wgt * bf2f((unsigned short)(pv & 0xffffu));
            a1 += wgt * bf2f((unsigned short)(pv >> 16));
        }
    }
    size_t o = (size_t)nnode * DIM + tid * 2;
    attn[o]     = f2bf(a0 * inv);
    attn[o + 1] = f2bf(a1 * inv);
}

// ---------------- expmap0 in-place on fp32: h *= tanh(||h||)/||h|| ------------
__global__ __launch_bounds__(64) void k_expmap(float* h) {
    int row = blockIdx.x, lane = threadIdx.x;
    floatx4* hp = (floatx4*)(h + (size_t)row * DIM + lane * 8);
    floatx4 h0 = hp[0], h1 = hp[1];
    float ss = 0.f;
#pragma unroll
    for (int i = 0; i < 4; i++) { ss += h0[i] * h0[i]; ss += h1[i] * h1[i]; }
#pragma unroll
    for (int off = 32; off >= 1; off >>= 1) ss += __shfl_xor(ss, off, 64);
    float n  = sqrtf(ss);
    float nc = fmaxf(n, 1e-7f);
    float fac = tanhf(nc) / nc;
#pragma unroll
    for (int i = 0; i < 4; i++) { h0[i] *= fac; h1[i] *= fac; }
    hp[0] = h0; hp[1] = h1;
}

extern "C" void kernel_launch(void* const* d_in, const int* in_sizes, int n_in,
                              void* d_out, int out_size, void* d_ws, size_t ws_size,
                              hipStream_t stream) {
    const float* x  = (const float*)d_in[0];
    const int* src  = (const int*)d_in[1];
    const int* dst  = (const int*)d_in[2];
    const float* Wq = (const float*)d_in[3];
    const float* bq = (const float*)d_in[4];
    const float* Wk = (const float*)d_in[5];
    const float* bk = (const float*)d_in[6];
    const float* Wv = (const float*)d_in[7];
    const float* bv = (const float*)d_in[8];
    const float* Wo = (const float*)d_in[9];
    const float* bo = (const float*)d_in[10];
    float* out = (float*)d_out;   // [20000 x 512] fp32

    char* ws = (char*)d_ws;
    const size_t A = (size_t)NND * DIM * 2;       // 20,480,000 B per bf16 [N,D] buffer
    const size_t WB = (size_t)DIM * DIM * 2;      // 524,288 B per bf16 [D,D] weight
    unsigned short* t  = (unsigned short*)(ws);   // later reused as attn
    unsigned short* qb = (unsigned short*)(ws + A);
    unsigned short* kb = (unsigned short*)(ws + 2 * A);
    unsigned short* vb = (unsigned short*)(ws + 3 * A);
    unsigned short* Wqb = (unsigned short*)(ws + 4 * A);
    unsigned short* Wkb = (unsigned short*)(ws + 4 * A + WB);
    unsigned short* Wvb = (unsigned short*)(ws + 4 * A + 2 * WB);
    unsigned short* Wob = (unsigned short*)(ws + 4 * A + 3 * WB);
    char* p = ws + 4 * A + 4 * WB;
    float* es   = (float*)p;                      // NE floats
    int* sorted = (int*)(p + (size_t)NE * 4);     // NE ints
    int* counts = (int*)(p + (size_t)NE * 8);     // NND
    int* offsets = counts + NND;                  // NND+1
    int* pos     = offsets + NND + 2;             // NND
    unsigned short* attn = t;                     // overlay (t dead after q/k/v gemms)

    hipMemsetAsync(counts, 0, (size_t)NND * 4, stream);

    const int W4 = DIM * DIM / 4;                 // 65536 float4 groups
    k_cvt<<<W4 / 256, 256, 0, stream>>>(Wq, Wqb, W4);
    k_cvt<<<W4 / 256, 256, 0, stream>>>(Wk, Wkb, W4);
    k_cvt<<<W4 / 256, 256, 0, stream>>>(Wv, Wvb, W4);
    k_cvt<<<W4 / 256, 256, 0, stream>>>(Wo, Wob, W4);

    k_logmap<<<NND, 64, 0, stream>>>(x, t);

    const float scale = 0.04419417382415922f;     // 1/sqrt(512)
    k_gemm<<<2500, 256, 0, stream>>>(t, Wqb, bq, qb, nullptr, scale, NND);
    k_gemm<<<2500, 256, 0, stream>>>(t, Wkb, bk, kb, nullptr, 1.0f, NND);
    k_gemm<<<2500, 256, 0, stream>>>(t, Wvb, bv, vb, nullptr, 1.0f, NND);

    k_hist<<<(NE + 255) / 256, 256, 0, stream>>>(dst, counts);
    k_scan<<<1, 1024, 0, stream>>>(counts, offsets, pos);
    k_scatter<<<(NE + 255) / 256, 256, 0, stream>>>(dst, pos, sorted);

    k_score<<<NE / 4, 256, 0, stream>>>(qb, kb, src, dst, es);
    k_agg<<<NND, 256, 0, stream>>>(offsets, sorted, src, es, vb, attn);

    k_gemm<<<2500, 256, 0, stream>>>(attn, Wob, bo, nullptr, out, 1.0f, NND);
    k_expmap<<<NND, 64, 0, stream>>>(out);
}

// Round 3
// 383.918 us; speedup vs baseline: 1.8058x; 1.8058x over previous
//
#include <hip/hip_runtime.h>
#include <math.h>
#include <stdint.h>

#define NND 20000
#define DIMK 512
#define NE  320000

typedef __attribute__((ext_vector_type(8))) short short8;
typedef __attribute__((ext_vector_type(4))) short short4v;
typedef __attribute__((ext_vector_type(4))) float floatx4;

__device__ inline float bf2f(unsigned short h) {
    unsigned int u = ((unsigned int)h) << 16;
    return __uint_as_float(u);
}
__device__ inline unsigned short f2bf(float f) {
    unsigned int u = __float_as_uint(f);
    unsigned int r = (u + 0x7fffu + ((u >> 16) & 1u)) >> 16;
    return (unsigned short)r;
}

// async global->LDS, 16B per lane; lds dest = wave-uniform base + lane*16
__device__ __forceinline__ void gld_lds16(const unsigned short* g, unsigned short* l) {
    __builtin_amdgcn_global_load_lds(
        (const __attribute__((address_space(1))) void*)g,
        (__attribute__((address_space(3))) void*)l,
        16, 0, 0);
}

// ---------------- fp32 -> bf16 conversion with scale fold ---------------------
__global__ __launch_bounds__(256) void k_cvt(const float* __restrict__ in,
                                             unsigned short* __restrict__ out,
                                             float scale, int n4) {
    int i = blockIdx.x * 256 + threadIdx.x;
    if (i >= n4) return;
    floatx4 f = *(const floatx4*)(in + (size_t)i * 4);
    union { short4v v; unsigned short u[4]; } o;
#pragma unroll
    for (int j = 0; j < 4; j++) o.u[j] = f2bf(f[j] * scale);
    *(short4v*)(out + (size_t)i * 4) = o.v;
}

// fused bias [1536]: [bq*scale | bk | bv]
__global__ void k_bias(const float* __restrict__ bq, const float* __restrict__ bk,
                       const float* __restrict__ bv, float* __restrict__ biasf,
                       float scale) {
    int i = blockIdx.x * 256 + threadIdx.x;
    if (i < 512) biasf[i] = bq[i] * scale;
    else if (i < 1024) biasf[i] = bk[i - 512];
    else if (i < 1536) biasf[i] = bv[i - 1024];
}

// ---------------- logmap0: t = atanh(||x||)/||x|| * x  (fp32 in, bf16 out) ----
__global__ __launch_bounds__(64) void k_logmap(const float* __restrict__ x,
                                               unsigned short* __restrict__ t) {
    int row = blockIdx.x;
    int lane = threadIdx.x;
    const floatx4* xp = (const floatx4*)(x + (size_t)row * DIMK + lane * 8);
    floatx4 x0 = xp[0], x1 = xp[1];
    float ss = 0.f;
#pragma unroll
    for (int i = 0; i < 4; i++) { ss += x0[i] * x0[i]; ss += x1[i] * x1[i]; }
#pragma unroll
    for (int off = 32; off >= 1; off >>= 1) ss += __shfl_xor(ss, off, 64);
    float n  = sqrtf(ss);
    float nc = fminf(fmaxf(n, 1e-7f), 1.0f - 1e-6f);
    float fac = atanhf(nc) / nc;
    union { short8 v; unsigned short u[8]; } o;
#pragma unroll
    for (int i = 0; i < 4; i++) { o.u[i] = f2bf(fac * x0[i]); o.u[4 + i] = f2bf(fac * x1[i]); }
    *(short8*)(t + (size_t)row * DIMK + lane * 8) = o.v;
}

// ---------------- m97-style GEMM: C[M x Ncols] = A[M x 512] @ B[Ncols x 512]^T + bias
// 256 thr = 4 waves; block tile 128M x 128N; BK=32; LDS staged via global_load_lds.
__global__ __launch_bounds__(256) void k_gemm(const unsigned short* __restrict__ A,
                                              const unsigned short* __restrict__ B,
                                              const float* __restrict__ biasf,
                                              unsigned short* __restrict__ out_bf,
                                              float* __restrict__ out_f,
                                              int M, int NT, int Ncols) {
    __shared__ unsigned short As[128 * 32];   // [tile_row][k] row-major, 64 B rows
    __shared__ unsigned short Bs[128 * 32];
    int bx = blockIdx.x;
    int mt = bx / NT, nt = bx % NT;
    int m0 = mt * 128, n0 = nt * 128;
    int tid = threadIdx.x, wv = tid >> 6, ln = tid & 63;
    int lr = ln & 15, qd = ln >> 4;
    int mh = wv >> 1, nh = wv & 1;

    floatx4 acc[4][4] = {};
    int srow = wv * 16 + (ln >> 2);          // staged tile row (pass p adds 64)
    int scol = (ln & 3) * 8;                 // k element offset within BK

    for (int kb = 0; kb < DIMK; kb += 32) {
        __syncthreads();
#pragma unroll
        for (int p = 0; p < 2; p++) {
            int tr = p * 64 + srow;
            int ar = m0 + tr; if (ar > M - 1) ar = M - 1;
            gld_lds16(A + (size_t)ar * DIMK + kb + scol,
                      (unsigned short*)((char*)As + (p * 64 + wv * 16) * 64));
            int br = n0 + tr;
            gld_lds16(B + (size_t)br * DIMK + kb + scol,
                      (unsigned short*)((char*)Bs + (p * 64 + wv * 16) * 64));
        }
        __syncthreads();
        short8 af[4], bfr[4];
#pragma unroll
        for (int mi = 0; mi < 4; mi++)
            af[mi] = *(const short8*)((const char*)As + (mh * 64 + mi * 16 + lr) * 64 + qd * 16);
#pragma unroll
        for (int ni = 0; ni < 4; ni++)
            bfr[ni] = *(const short8*)((const char*)Bs + (nh * 64 + ni * 16 + lr) * 64 + qd * 16);
#pragma unroll
        for (int mi = 0; mi < 4; mi++)
#pragma unroll
            for (int ni = 0; ni < 4; ni++)
                acc[mi][ni] = __builtin_amdgcn_mfma_f32_16x16x32_bf16(af[mi], bfr[ni], acc[mi][ni], 0, 0, 0);
    }

#pragma unroll
    for (int ni = 0; ni < 4; ni++) {
        int gn = n0 + nh * 64 + ni * 16 + lr;
        float bv = biasf[gn];
#pragma unroll
        for (int mi = 0; mi < 4; mi++) {
            int gm0 = m0 + mh * 64 + mi * 16 + qd * 4;
#pragma unroll
            for (int r = 0; r < 4; r++) {
                int gm = gm0 + r;
                if (gm < M) {
                    float val = acc[mi][ni][r] + bv;
                    if (out_bf) out_bf[(size_t)gm * Ncols + gn] = f2bf(val);
                    else        out_f [(size_t)gm * Ncols + gn] = val;
                }
            }
        }
    }
}

// ---------------- CSR build ---------------------------------------------------
__global__ void k_hist(const int* __restrict__ dst, int* __restrict__ counts) {
    int e = blockIdx.x * 256 + threadIdx.x;
    if (e < NE) atomicAdd(&counts[dst[e]], 1);
}

__global__ __launch_bounds__(1024) void k_scan(const int* __restrict__ counts,
                                               int* __restrict__ offsets,
                                               int* __restrict__ pos) {
    const int C = 20;  // 1024*20 = 20480 >= 20000
    __shared__ int wsum[16];
    __shared__ int wpre[16];
    int tid = threadIdx.x, lane = tid & 63, w = tid >> 6;
    int local[C];
    int run = 0;
#pragma unroll
    for (int i = 0; i < C; i++) {
        int idx = tid * C + i;
        int c = (idx < NND) ? counts[idx] : 0;
        local[i] = run; run += c;
    }
    int v = run;
#pragma unroll
    for (int off = 1; off < 64; off <<= 1) {
        int u = __shfl_up(v, off, 64);
        if (lane >= off) v += u;
    }
    if (lane == 63) wsum[w] = v;
    __syncthreads();
    if (tid == 0) { int acc = 0; for (int i = 0; i < 16; i++) { wpre[i] = acc; acc += wsum[i]; } }
    __syncthreads();
    int texcl = wpre[w] + (v - run);
#pragma unroll
    for (int i = 0; i < C; i++) {
        int idx = tid * C + i;
        if (idx < NND) { int o = texcl + local[i]; offsets[idx] = o; pos[idx] = o; }
    }
    if (tid == 1023) offsets[NND] = texcl + run;
}

__global__ void k_scatter(const int* __restrict__ dst, int* __restrict__ pos,
                          int* __restrict__ sorted) {
    int e = blockIdx.x * 256 + threadIdx.x;
    if (e < NE) { int p = atomicAdd(&pos[dst[e]], 1); sorted[p] = e; }
}

// ---------------- fused score+softmax+aggregate (single pass, no max needed) --
// qkv row layout: [q(512) | k(512) | v(512)], stride 1536
__global__ __launch_bounds__(256) void k_fsa(const int* __restrict__ offsets,
                                             const int* __restrict__ sorted,
                                             const int* __restrict__ src,
                                             const unsigned short* __restrict__ qkv,
                                             unsigned short* __restrict__ attn) {
    __shared__ float sacc[4][512];
    __shared__ float sden[4];
    int n = blockIdx.x, tid = threadIdx.x, wv = tid >> 6, ln = tid & 63;
    int beg = offsets[n], end = offsets[n + 1];
    short8 qv = *(const short8*)(qkv + (size_t)n * 1536 + ln * 8);
    float qf[8];
#pragma unroll
    for (int j = 0; j < 8; j++) qf[j] = bf2f((unsigned short)qv[j]);
    float av[8] = {0, 0, 0, 0, 0, 0, 0, 0};
    float den = 0.f;
    for (int i = beg + wv; i < end; i += 4) {
        int s = src[sorted[i]];
        const unsigned short* base = qkv + (size_t)s * 1536;
        short8 kv = *(const short8*)(base + 512 + ln * 8);
        float d = 0.f;
#pragma unroll
        for (int j = 0; j < 8; j++) d += qf[j] * bf2f((unsigned short)kv[j]);
#pragma unroll
        for (int off = 32; off >= 1; off >>= 1) d += __shfl_xor(d, off, 64);
        float wgt = expf(d);
        den += wgt;
        short8 vv = *(const short8*)(base + 1024 + ln * 8);
#pragma unroll
        for (int j = 0; j < 8; j++) av[j] += wgt * bf2f((unsigned short)vv[j]);
    }
#pragma unroll
    for (int j = 0; j < 8; j++) sacc[wv][ln * 8 + j] = av[j];
    if (ln == 0) sden[wv] = den;
    __syncthreads();
    float dtot = sden[0] + sden[1] + sden[2] + sden[3];
    float inv = 1.0f / dtot;
    int c = tid * 2;
    float t0 = sacc[0][c] + sacc[1][c] + sacc[2][c] + sacc[3][c];
    float t1 = sacc[0][c + 1] + sacc[1][c + 1] + sacc[2][c + 1] + sacc[3][c + 1];
    attn[(size_t)n * 512 + c]     = f2bf(t0 * inv);
    attn[(size_t)n * 512 + c + 1] = f2bf(t1 * inv);
}

// ---------------- expmap0 in-place on fp32: h *= tanh(||h||)/||h|| ------------
__global__ __launch_bounds__(64) void k_expmap(float* h) {
    int row = blockIdx.x, lane = threadIdx.x;
    floatx4* hp = (floatx4*)(h + (size_t)row * DIMK + lane * 8);
    floatx4 h0 = hp[0], h1 = hp[1];
    float ss = 0.f;
#pragma unroll
    for (int i = 0; i < 4; i++) { ss += h0[i] * h0[i]; ss += h1[i] * h1[i]; }
#pragma unroll
    for (int off = 32; off >= 1; off >>= 1) ss += __shfl_xor(ss, off, 64);
    float n  = sqrtf(ss);
    float nc = fmaxf(n, 1e-7f);
    float fac = tanhf(nc) / nc;
#pragma unroll
    for (int i = 0; i < 4; i++) { h0[i] *= fac; h1[i] *= fac; }
    hp[0] = h0; hp[1] = h1;
}

extern "C" void kernel_launch(void* const* d_in, const int* in_sizes, int n_in,
                              void* d_out, int out_size, void* d_ws, size_t ws_size,
                              hipStream_t stream) {
    const float* x  = (const float*)d_in[0];
    const int* src  = (const int*)d_in[1];
    const int* dst  = (const int*)d_in[2];
    const float* Wq = (const float*)d_in[3];
    const float* bq = (const float*)d_in[4];
    const float* Wk = (const float*)d_in[5];
    const float* bk = (const float*)d_in[6];
    const float* Wv = (const float*)d_in[7];
    const float* bv = (const float*)d_in[8];
    const float* Wo = (const float*)d_in[9];
    const float* bo = (const float*)d_in[10];
    float* out = (float*)d_out;   // [20000 x 512] fp32

    char* ws = (char*)d_ws;
    const size_t TB = (size_t)NND * DIMK * 2;        // t / attn buffer: 20.48 MB
    const size_t QB = (size_t)NND * 1536 * 2;        // qkv buffer: 61.44 MB
    const size_t WB = (size_t)DIMK * DIMK * 2;       // 0.52 MB per weight
    unsigned short* t    = (unsigned short*)(ws);    // also attn overlay
    unsigned short* qkv  = (unsigned short*)(ws + TB);
    unsigned short* Wqkv = (unsigned short*)(ws + TB + QB);          // [1536 x 512]
    unsigned short* Wob  = (unsigned short*)(ws + TB + QB + 3 * WB); // [512 x 512]
    float* biasf         = (float*)(ws + TB + QB + 4 * WB);          // [1536]
    char* p = ws + TB + QB + 4 * WB + 1536 * 4;
    int* sorted  = (int*)p;                          // NE
    int* counts  = sorted + NE;                      // NND
    int* offsets = counts + NND;                     // NND+1
    int* pos     = offsets + NND + 2;                // NND
    unsigned short* attn = t;                        // t dead after qkv GEMM

    hipMemsetAsync(counts, 0, (size_t)NND * 4, stream);

    const float scale = 0.04419417382415922f;        // 1/sqrt(512)
    const int W4 = DIMK * DIMK / 4;                  // 65536
    k_cvt<<<W4 / 256, 256, 0, stream>>>(Wq, Wqkv,                 scale, W4);
    k_cvt<<<W4 / 256, 256, 0, stream>>>(Wk, Wqkv + 512 * DIMK,    1.0f,  W4);
    k_cvt<<<W4 / 256, 256, 0, stream>>>(Wv, Wqkv + 1024 * DIMK,   1.0f,  W4);
    k_cvt<<<W4 / 256, 256, 0, stream>>>(Wo, Wob,                  1.0f,  W4);
    k_bias<<<6, 256, 0, stream>>>(bq, bk, bv, biasf, scale);

    k_logmap<<<NND, 64, 0, stream>>>(x, t);

    k_hist<<<(NE + 255) / 256, 256, 0, stream>>>(dst, counts);
    k_scan<<<1, 1024, 0, stream>>>(counts, offsets, pos);
    k_scatter<<<(NE + 255) / 256, 256, 0, stream>>>(dst, pos, sorted);

    // fused q/k/v GEMM: [20000 x 1536]
    k_gemm<<<157 * 12, 256, 0, stream>>>(t, Wqkv, biasf, qkv, nullptr, NND, 12, 1536);

    k_fsa<<<NND, 256, 0, stream>>>(offsets, sorted, src, qkv, attn);

    // output projection straight into d_out (fp32), then expmap in place
    k_gemm<<<157 * 4, 256, 0, stream>>>(attn, Wob, bo, nullptr, out, NND, 4, 512);
    k_expmap<<<NND, 64, 0, stream>>>(out);
}

// Round 4
// 334.134 us; speedup vs baseline: 2.0749x; 1.1490x over previous
//
#include <hip/hip_runtime.h>
#include <math.h>
#include <stdint.h>

#define NND 20000
#define DIMK 512
#define NE  320000

typedef __attribute__((ext_vector_type(8))) short short8;
typedef __attribute__((ext_vector_type(4))) short short4v;
typedef __attribute__((ext_vector_type(4))) float floatx4;

__device__ inline float bf2f(unsigned short h) {
    unsigned int u = ((unsigned int)h) << 16;
    return __uint_as_float(u);
}
__device__ inline unsigned short f2bf(float f) {
    unsigned int u = __float_as_uint(f);
    unsigned int r = (u + 0x7fffu + ((u >> 16) & 1u)) >> 16;
    return (unsigned short)r;
}

__device__ __forceinline__ void gld_lds16(const unsigned short* g, unsigned short* l) {
    __builtin_amdgcn_global_load_lds(
        (const __attribute__((address_space(1))) void*)g,
        (__attribute__((address_space(3))) void*)l,
        16, 0, 0);
}

// ---------------- all four W matrices fp32 -> bf16 (scale folded into Wq) ----
__global__ __launch_bounds__(256) void k_cvt_all(const float* __restrict__ Wq,
                                                 const float* __restrict__ Wk,
                                                 const float* __restrict__ Wv,
                                                 const float* __restrict__ Wo,
                                                 unsigned short* __restrict__ Wqkv,
                                                 unsigned short* __restrict__ Wob,
                                                 float scale) {
    int i = blockIdx.x * 256 + threadIdx.x;     // 0 .. 4*65536
    int m = i >> 16, j = i & 65535;
    const float* in; unsigned short* out; float sc = 1.0f;
    if (m == 0)      { in = Wq; out = Wqkv;               sc = scale; }
    else if (m == 1) { in = Wk; out = Wqkv + 512 * DIMK; }
    else if (m == 2) { in = Wv; out = Wqkv + 1024 * DIMK; }
    else             { in = Wo; out = Wob; }
    floatx4 f = *(const floatx4*)(in + (size_t)j * 4);
    union { short4v v; unsigned short u[4]; } o;
#pragma unroll
    for (int t = 0; t < 4; t++) o.u[t] = f2bf(f[t] * sc);
    *(short4v*)(out + (size_t)j * 4) = o.v;
}

__global__ void k_bias(const float* __restrict__ bq, const float* __restrict__ bk,
                       const float* __restrict__ bv, float* __restrict__ biasf,
                       float scale) {
    int i = blockIdx.x * 256 + threadIdx.x;
    if (i < 512) biasf[i] = bq[i] * scale;
    else if (i < 1024) biasf[i] = bk[i - 512];
    else if (i < 1536) biasf[i] = bv[i - 1024];
}

// ---------------- logmap0 -----------------------------------------------------
__global__ __launch_bounds__(64) void k_logmap(const float* __restrict__ x,
                                               unsigned short* __restrict__ t) {
    int row = blockIdx.x, lane = threadIdx.x;
    const floatx4* xp = (const floatx4*)(x + (size_t)row * DIMK + lane * 8);
    floatx4 x0 = xp[0], x1 = xp[1];
    float ss = 0.f;
#pragma unroll
    for (int i = 0; i < 4; i++) { ss += x0[i] * x0[i]; ss += x1[i] * x1[i]; }
#pragma unroll
    for (int off = 32; off >= 1; off >>= 1) ss += __shfl_xor(ss, off, 64);
    float n  = sqrtf(ss);
    float nc = fminf(fmaxf(n, 1e-7f), 1.0f - 1e-6f);
    float fac = atanhf(nc) / nc;
    union { short8 v; unsigned short u[8]; } o;
#pragma unroll
    for (int i = 0; i < 4; i++) { o.u[i] = f2bf(fac * x0[i]); o.u[4 + i] = f2bf(fac * x1[i]); }
    *(short8*)(t + (size_t)row * DIMK + lane * 8) = o.v;
}

// ---------------- double-buffered m97-style GEMM ------------------------------
// C[M x Ncols] = A[M x 512] @ B[Ncols x 512]^T + bias.  Block tile 128x128, BK=32.
// XCD swizzle: xcd = blockIdx%8 owns mt = xcd (mod 8) -> disjoint L2-resident A.
__global__ __launch_bounds__(256) void k_gemm(const unsigned short* __restrict__ A,
                                              const unsigned short* __restrict__ B,
                                              const float* __restrict__ biasf,
                                              unsigned short* __restrict__ out_bf,
                                              float* __restrict__ out_f,
                                              int M, int MT, int NT, int Ncols) {
    __shared__ unsigned short smem[16384];      // As[2]:0..8191, Bs[2]:8192..16383
    int b = blockIdx.x;
    int xcd = b & 7, i = b >> 3;
    int nt = i % NT, mt = (i / NT) * 8 + xcd;
    if (mt >= MT) return;
    int m0 = mt * 128, n0 = nt * 128;
    int tid = threadIdx.x, wv = tid >> 6, ln = tid & 63;
    int lr = ln & 15, qd = ln >> 4;
    int mh = wv >> 1, nh = wv & 1;

    floatx4 acc[4][4] = {};
    int srow = wv * 16 + (ln >> 2);
    int scol = (ln & 3) * 8;

    // prologue: stage k-block 0 into buffer 0
    {
        unsigned short* Ab = smem;
        unsigned short* Bb = smem + 8192;
#pragma unroll
        for (int p = 0; p < 2; p++) {
            int tr = p * 64 + srow;
            int ar = m0 + tr; if (ar > M - 1) ar = M - 1;
            gld_lds16(A + (size_t)ar * DIMK + scol, Ab + (p * 64 + wv * 16) * 32);
            gld_lds16(B + (size_t)(n0 + tr) * DIMK + scol, Bb + (p * 64 + wv * 16) * 32);
        }
    }

    for (int it = 0; it < 16; it++) {
        int cur = it & 1, nxt = cur ^ 1;
        __syncthreads();                        // buf[cur] ready; nxt free
        if (it + 1 < 16) {
            int kb = (it + 1) * 32;
            unsigned short* Ab = smem + nxt * 4096;
            unsigned short* Bb = smem + 8192 + nxt * 4096;
#pragma unroll
            for (int p = 0; p < 2; p++) {
                int tr = p * 64 + srow;
                int ar = m0 + tr; if (ar > M - 1) ar = M - 1;
                gld_lds16(A + (size_t)ar * DIMK + kb + scol, Ab + (p * 64 + wv * 16) * 32);
                gld_lds16(B + (size_t)(n0 + tr) * DIMK + kb + scol, Bb + (p * 64 + wv * 16) * 32);
            }
        }
        const unsigned short* Ac = smem + cur * 4096;
        const unsigned short* Bc = smem + 8192 + cur * 4096;
        short8 af[4], bfr[4];
#pragma unroll
        for (int mi = 0; mi < 4; mi++)
            af[mi] = *(const short8*)(Ac + (mh * 64 + mi * 16 + lr) * 32 + qd * 8);
#pragma unroll
        for (int ni = 0; ni < 4; ni++)
            bfr[ni] = *(const short8*)(Bc + (nh * 64 + ni * 16 + lr) * 32 + qd * 8);
#pragma unroll
        for (int mi = 0; mi < 4; mi++)
#pragma unroll
            for (int ni = 0; ni < 4; ni++)
                acc[mi][ni] = __builtin_amdgcn_mfma_f32_16x16x32_bf16(af[mi], bfr[ni], acc[mi][ni], 0, 0, 0);
    }

    float bb[4];
#pragma unroll
    for (int ni = 0; ni < 4; ni++) bb[ni] = biasf[n0 + nh * 64 + ni * 16 + lr];

    if (out_bf) {
        // coalesced epilogue via LDS: 4 chunks of 32 rows x 128 cols bf16 (8 KB)
        unsigned short* cs = smem;
#pragma unroll
        for (int g = 0; g < 4; g++) {
            __syncthreads();
            if (mh == (g >> 1)) {
                int miB = (g & 1) * 2;
#pragma unroll
                for (int m2 = 0; m2 < 2; m2++) {
                    int mi = miB + m2;
                    int lrow = mi * 16 + qd * 4 - (g & 1) * 32;
#pragma unroll
                    for (int ni = 0; ni < 4; ni++) {
                        int col = nh * 64 + ni * 16 + lr;
#pragma unroll
                        for (int r = 0; r < 4; r++)
                            cs[(lrow + r) * 128 + col] = f2bf(acc[mi][ni][r] + bb[ni]);
                    }
                }
            }
            __syncthreads();
#pragma unroll
            for (int itr = 0; itr < 2; itr++) {
                int slot = itr * 256 + tid;
                int row = slot >> 4, cg = slot & 15;
                int gm = m0 + g * 32 + row;
                if (gm < M) {
                    short8 vv = *(const short8*)(cs + row * 128 + cg * 8);
                    *(short8*)(out_bf + (size_t)gm * Ncols + n0 + cg * 8) = vv;
                }
            }
        }
    } else {
#pragma unroll
        for (int ni = 0; ni < 4; ni++) {
            int gn = n0 + nh * 64 + ni * 16 + lr;
#pragma unroll
            for (int mi = 0; mi < 4; mi++) {
                int gm0 = m0 + mh * 64 + mi * 16 + qd * 4;
#pragma unroll
                for (int r = 0; r < 4; r++) {
                    int gm = gm0 + r;
                    if (gm < M) out_f[(size_t)gm * Ncols + gn] = acc[mi][ni][r] + bb[ni];
                }
            }
        }
    }
}

// ---------------- CSR build ---------------------------------------------------
__global__ void k_hist(const int* __restrict__ dst, int* __restrict__ counts) {
    int e = blockIdx.x * 256 + threadIdx.x;
    if (e < NE) atomicAdd(&counts[dst[e]], 1);
}

__global__ __launch_bounds__(1024) void k_scan(const int* __restrict__ counts,
                                               int* __restrict__ offsets,
                                               int* __restrict__ pos) {
    const int C = 20;
    __shared__ int wsum[16];
    __shared__ int wpre[16];
    int tid = threadIdx.x, lane = tid & 63, w = tid >> 6;
    int local[C];
    int run = 0;
#pragma unroll
    for (int i = 0; i < C; i++) {
        int idx = tid * C + i;
        int c = (idx < NND) ? counts[idx] : 0;
        local[i] = run; run += c;
    }
    int v = run;
#pragma unroll
    for (int off = 1; off < 64; off <<= 1) {
        int u = __shfl_up(v, off, 64);
        if (lane >= off) v += u;
    }
    if (lane == 63) wsum[w] = v;
    __syncthreads();
    if (tid == 0) { int acc = 0; for (int i = 0; i < 16; i++) { wpre[i] = acc; acc += wsum[i]; } }
    __syncthreads();
    int texcl = wpre[w] + (v - run);
#pragma unroll
    for (int i = 0; i < C; i++) {
        int idx = tid * C + i;
        if (idx < NND) { int o = texcl + local[i]; offsets[idx] = o; pos[idx] = o; }
    }
    if (tid == 1023) offsets[NND] = texcl + run;
}

// stores src[e] directly (sorted-by-dst source list)
__global__ void k_scatter(const int* __restrict__ dst, const int* __restrict__ src,
                          int* __restrict__ pos, int* __restrict__ ssrc) {
    int e = blockIdx.x * 256 + threadIdx.x;
    if (e < NE) { int p = atomicAdd(&pos[dst[e]], 1); ssrc[p] = src[e]; }
}

// ---------------- fused score+softmax+aggregate -------------------------------
// qkv row: [q(512) | k(512) | v(512)], stride 1536. Block per node, 4 waves,
// 2 edges per wave iteration for ILP. No max-subtraction (|score| <= ~0.2).
__global__ __launch_bounds__(256) void k_fsa(const int* __restrict__ offsets,
                                             const int* __restrict__ ssrc,
                                             const unsigned short* __restrict__ qkv,
                                             unsigned short* __restrict__ attn) {
    __shared__ float sacc[4][512];
    __shared__ float sden[4];
    int n = blockIdx.x, tid = threadIdx.x, wv = tid >> 6, ln = tid & 63;
    int beg = offsets[n], end = offsets[n + 1];
    short8 qv = *(const short8*)(qkv + (size_t)n * 1536 + ln * 8);
    float qf[8];
#pragma unroll
    for (int j = 0; j < 8; j++) qf[j] = bf2f((unsigned short)qv[j]);
    float av[8] = {0, 0, 0, 0, 0, 0, 0, 0};
    float den = 0.f;
    int i = beg + wv * 2;
    for (; i + 1 < end; i += 8) {
        int s0 = ssrc[i], s1 = ssrc[i + 1];
        const unsigned short* b0 = qkv + (size_t)s0 * 1536;
        const unsigned short* b1 = qkv + (size_t)s1 * 1536;
        short8 k0 = *(const short8*)(b0 + 512 + ln * 8);
        short8 k1 = *(const short8*)(b1 + 512 + ln * 8);
        float d0 = 0.f, d1 = 0.f;
#pragma unroll
        for (int j = 0; j < 8; j++) {
            d0 += qf[j] * bf2f((unsigned short)k0[j]);
            d1 += qf[j] * bf2f((unsigned short)k1[j]);
        }
#pragma unroll
        for (int off = 32; off >= 1; off >>= 1) {
            d0 += __shfl_xor(d0, off, 64);
            d1 += __shfl_xor(d1, off, 64);
        }
        float w0 = expf(d0), w1 = expf(d1);
        den += w0 + w1;
        short8 v0 = *(const short8*)(b0 + 1024 + ln * 8);
        short8 v1 = *(const short8*)(b1 + 1024 + ln * 8);
#pragma unroll
        for (int j = 0; j < 8; j++)
            av[j] += w0 * bf2f((unsigned short)v0[j]) + w1 * bf2f((unsigned short)v1[j]);
    }
    if (i < end) {
        int s0 = ssrc[i];
        const unsigned short* b0 = qkv + (size_t)s0 * 1536;
        short8 k0 = *(const short8*)(b0 + 512 + ln * 8);
        float d0 = 0.f;
#pragma unroll
        for (int j = 0; j < 8; j++) d0 += qf[j] * bf2f((unsigned short)k0[j]);
#pragma unroll
        for (int off = 32; off >= 1; off >>= 1) d0 += __shfl_xor(d0, off, 64);
        float w0 = expf(d0);
        den += w0;
        short8 v0 = *(const short8*)(b0 + 1024 + ln * 8);
#pragma unroll
        for (int j = 0; j < 8; j++) av[j] += w0 * bf2f((unsigned short)v0[j]);
    }
#pragma unroll
    for (int j = 0; j < 8; j++) sacc[wv][ln * 8 + j] = av[j];
    if (ln == 0) sden[wv] = den;
    __syncthreads();
    float inv = 1.0f / (sden[0] + sden[1] + sden[2] + sden[3]);
    int c = tid * 2;
    float t0 = sacc[0][c] + sacc[1][c] + sacc[2][c] + sacc[3][c];
    float t1 = sacc[0][c + 1] + sacc[1][c + 1] + sacc[2][c + 1] + sacc[3][c + 1];
    attn[(size_t)n * 512 + c]     = f2bf(t0 * inv);
    attn[(size_t)n * 512 + c + 1] = f2bf(t1 * inv);
}

// ---------------- expmap0 in place --------------------------------------------
__global__ __launch_bounds__(64) void k_expmap(float* h) {
    int row = blockIdx.x, lane = threadIdx.x;
    floatx4* hp = (floatx4*)(h + (size_t)row * DIMK + lane * 8);
    floatx4 h0 = hp[0], h1 = hp[1];
    float ss = 0.f;
#pragma unroll
    for (int i = 0; i < 4; i++) { ss += h0[i] * h0[i]; ss += h1[i] * h1[i]; }
#pragma unroll
    for (int off = 32; off >= 1; off >>= 1) ss += __shfl_xor(ss, off, 64);
    float n  = sqrtf(ss);
    float nc = fmaxf(n, 1e-7f);
    float fac = tanhf(nc) / nc;
#pragma unroll
    for (int i = 0; i < 4; i++) { h0[i] *= fac; h1[i] *= fac; }
    hp[0] = h0; hp[1] = h1;
}

extern "C" void kernel_launch(void* const* d_in, const int* in_sizes, int n_in,
                              void* d_out, int out_size, void* d_ws, size_t ws_size,
                              hipStream_t stream) {
    const float* x  = (const float*)d_in[0];
    const int* src  = (const int*)d_in[1];
    const int* dst  = (const int*)d_in[2];
    const float* Wq = (const float*)d_in[3];
    const float* bq = (const float*)d_in[4];
    const float* Wk = (const float*)d_in[5];
    const float* bk = (const float*)d_in[6];
    const float* Wv = (const float*)d_in[7];
    const float* bv = (const float*)d_in[8];
    const float* Wo = (const float*)d_in[9];
    const float* bo = (const float*)d_in[10];
    float* out = (float*)d_out;

    char* ws = (char*)d_ws;
    const size_t TB = (size_t)NND * DIMK * 2;
    const size_t QB = (size_t)NND * 1536 * 2;
    const size_t WB = (size_t)DIMK * DIMK * 2;
    unsigned short* t    = (unsigned short*)(ws);
    unsigned short* qkv  = (unsigned short*)(ws + TB);
    unsigned short* Wqkv = (unsigned short*)(ws + TB + QB);
    unsigned short* Wob  = (unsigned short*)(ws + TB + QB + 3 * WB);
    float* biasf         = (float*)(ws + TB + QB + 4 * WB);
    char* p = ws + TB + QB + 4 * WB + 1536 * 4;
    int* ssrc    = (int*)p;                       // NE
    int* counts  = ssrc + NE;                     // NND
    int* offsets = counts + NND;                  // NND+1
    int* pos     = offsets + NND + 2;             // NND
    unsigned short* attn = t;

    hipMemsetAsync(counts, 0, (size_t)NND * 4, stream);

    const float scale = 0.04419417382415922f;     // 1/sqrt(512)
    k_cvt_all<<<1024, 256, 0, stream>>>(Wq, Wk, Wv, Wo, Wqkv, Wob, scale);
    k_bias<<<6, 256, 0, stream>>>(bq, bk, bv, biasf, scale);

    k_logmap<<<NND, 64, 0, stream>>>(x, t);

    k_hist<<<(NE + 255) / 256, 256, 0, stream>>>(dst, counts);
    k_scan<<<1, 1024, 0, stream>>>(counts, offsets, pos);
    k_scatter<<<(NE + 255) / 256, 256, 0, stream>>>(dst, src, pos, ssrc);

    // fused q/k/v GEMM: [20000 x 1536]; grid = 8 xcd * 20 mt8 * 12 nt
    k_gemm<<<8 * 20 * 12, 256, 0, stream>>>(t, Wqkv, biasf, qkv, nullptr, NND, 157, 12, 1536);

    k_fsa<<<NND, 256, 0, stream>>>(offsets, ssrc, qkv, attn);

    // output projection (fp32 into d_out), expmap in place
    k_gemm<<<8 * 20 * 4, 256, 0, stream>>>(attn, Wob, bo, nullptr, out, NND, 157, 4, 512);
    k_expmap<<<NND, 64, 0, stream>>>(out);
}

// Round 5
// 312.366 us; speedup vs baseline: 2.2195x; 1.0697x over previous
//
#include <hip/hip_runtime.h>
#include <math.h>
#include <stdint.h>

#define NND 20000
#define DIMK 512
#define NE  320000

typedef __attribute__((ext_vector_type(8))) short short8;
typedef __attribute__((ext_vector_type(4))) float floatx4;
typedef __attribute__((ext_vector_type(2))) float float2v;

__device__ inline float bf2f(unsigned short h) {
    unsigned int u = ((unsigned int)h) << 16;
    return __uint_as_float(u);
}
__device__ inline unsigned short f2bf(float f) {
    unsigned int u = __float_as_uint(f);
    unsigned int r = (u + 0x7fffu + ((u >> 16) & 1u)) >> 16;
    return (unsigned short)r;
}
// unpack dword holding 2 bf16 -> float2
__device__ __forceinline__ float2v bfpair(unsigned int u) {
    float2v r;
    r.x = __uint_as_float(u << 16);
    r.y = __uint_as_float(u & 0xffff0000u);
    return r;
}

__device__ __forceinline__ void gld_lds16(const unsigned short* g, unsigned short* l) {
    __builtin_amdgcn_global_load_lds(
        (const __attribute__((address_space(1))) void*)g,
        (__attribute__((address_space(3))) void*)l,
        16, 0, 0);
}

// ---------------- fused pre-pass: logmap + W cvt (scales folded) + bias -------
// blocks [0,5000): logmap (4 rows each); [5000,6024): W cvt; [6024,6030): bias
__global__ __launch_bounds__(256) void k_pre(const float* __restrict__ x,
                                             const float* __restrict__ Wq,
                                             const float* __restrict__ Wk,
                                             const float* __restrict__ Wv,
                                             const float* __restrict__ Wo,
                                             const float* __restrict__ bq,
                                             const float* __restrict__ bk,
                                             const float* __restrict__ bv,
                                             unsigned short* __restrict__ t,
                                             unsigned short* __restrict__ Wqkv,
                                             unsigned short* __restrict__ Wob,
                                             float* __restrict__ biasf,
                                             float scale_q) {
    int blk = blockIdx.x, tid = threadIdx.x;
    if (blk < 5000) {
        int row = blk * 4 + (tid >> 6);
        int lane = tid & 63;
        const floatx4* xp = (const floatx4*)(x + (size_t)row * DIMK + lane * 8);
        floatx4 x0 = xp[0], x1 = xp[1];
        float ss = 0.f;
#pragma unroll
        for (int i = 0; i < 4; i++) { ss += x0[i] * x0[i]; ss += x1[i] * x1[i]; }
#pragma unroll
        for (int off = 32; off >= 1; off >>= 1) ss += __shfl_xor(ss, off, 64);
        float n  = sqrtf(ss);
        float nc = fminf(fmaxf(n, 1e-7f), 1.0f - 1e-6f);
        float fac = atanhf(nc) / nc;
        union { short8 v; unsigned short u[8]; } o;
#pragma unroll
        for (int i = 0; i < 4; i++) { o.u[i] = f2bf(fac * x0[i]); o.u[4 + i] = f2bf(fac * x1[i]); }
        *(short8*)(t + (size_t)row * DIMK + lane * 8) = o.v;
    } else if (blk < 6024) {
        int i = (blk - 5000) * 256 + tid;           // 0 .. 4*65536
        int m = i >> 16, j = i & 65535;
        const float* in; unsigned short* out; float sc = 1.0f;
        if (m == 0)      { in = Wq; out = Wqkv;               sc = scale_q; }
        else if (m == 1) { in = Wk; out = Wqkv + 512 * DIMK;  sc = 16.0f; }
        else if (m == 2) { in = Wv; out = Wqkv + 1024 * DIMK; }
        else             { in = Wo; out = Wob; }
        floatx4 f = *(const floatx4*)(in + (size_t)j * 4);
        union { unsigned long long d; unsigned short u[4]; } o;
#pragma unroll
        for (int q = 0; q < 4; q++) o.u[q] = f2bf(f[q] * sc);
        *(unsigned long long*)(out + (size_t)j * 4) = o.d;
    } else {
        int i = (blk - 6024) * 256 + tid;           // 0..1535
        if (i < 512) biasf[i] = bq[i] * scale_q;
        else if (i < 1024) biasf[i] = bk[i - 512] * 16.0f;
        else if (i < 1536) biasf[i] = bv[i - 1024];
    }
}

// ---------------- double-buffered GEMM, 128x128, BK=32, XCD swizzle -----------
// qkv mode (out_f==0): nt 0-3 -> q bf16, 4-7 -> k fp8 (x16 folded), 8-11 -> v bf16
// proj mode (out_f!=0): direct fp32 stores
__global__ __launch_bounds__(256) void k_gemm(const unsigned short* __restrict__ A,
                                              const unsigned short* __restrict__ B,
                                              const float* __restrict__ biasf,
                                              unsigned short* __restrict__ out_q,
                                              unsigned char*  __restrict__ out_k8,
                                              unsigned short* __restrict__ out_v,
                                              float* __restrict__ out_f,
                                              int M, int MT, int NT, int Ncols) {
    __shared__ unsigned short smem[16384];
    int b = blockIdx.x;
    int xcd = b & 7, i = b >> 3;
    int nt = i % NT, mt = (i / NT) * 8 + xcd;
    if (mt >= MT) return;
    int m0 = mt * 128, n0 = nt * 128;
    int tid = threadIdx.x, wv = tid >> 6, ln = tid & 63;
    int lr = ln & 15, qd = ln >> 4;
    int mh = wv >> 1, nh = wv & 1;

    floatx4 acc[4][4] = {};
    int srow = wv * 16 + (ln >> 2);
    int scol = (ln & 3) * 8;

    {
        unsigned short* Ab = smem;
        unsigned short* Bb = smem + 8192;
#pragma unroll
        for (int p = 0; p < 2; p++) {
            int tr = p * 64 + srow;
            int ar = m0 + tr; if (ar > M - 1) ar = M - 1;
            gld_lds16(A + (size_t)ar * DIMK + scol, Ab + (p * 64 + wv * 16) * 32);
            gld_lds16(B + (size_t)(n0 + tr) * DIMK + scol, Bb + (p * 64 + wv * 16) * 32);
        }
    }

    for (int it = 0; it < 16; it++) {
        int cur = it & 1, nxt = cur ^ 1;
        __syncthreads();
        if (it + 1 < 16) {
            int kb = (it + 1) * 32;
            unsigned short* Ab = smem + nxt * 4096;
            unsigned short* Bb = smem + 8192 + nxt * 4096;
#pragma unroll
            for (int p = 0; p < 2; p++) {
                int tr = p * 64 + srow;
                int ar = m0 + tr; if (ar > M - 1) ar = M - 1;
                gld_lds16(A + (size_t)ar * DIMK + kb + scol, Ab + (p * 64 + wv * 16) * 32);
                gld_lds16(B + (size_t)(n0 + tr) * DIMK + kb + scol, Bb + (p * 64 + wv * 16) * 32);
            }
        }
        const unsigned short* Ac = smem + cur * 4096;
        const unsigned short* Bc = smem + 8192 + cur * 4096;
        short8 af[4], bfr[4];
#pragma unroll
        for (int mi = 0; mi < 4; mi++)
            af[mi] = *(const short8*)(Ac + (mh * 64 + mi * 16 + lr) * 32 + qd * 8);
#pragma unroll
        for (int ni = 0; ni < 4; ni++)
            bfr[ni] = *(const short8*)(Bc + (nh * 64 + ni * 16 + lr) * 32 + qd * 8);
#pragma unroll
        for (int mi = 0; mi < 4; mi++)
#pragma unroll
            for (int ni = 0; ni < 4; ni++)
                acc[mi][ni] = __builtin_amdgcn_mfma_f32_16x16x32_bf16(af[mi], bfr[ni], acc[mi][ni], 0, 0, 0);
    }

    float bb[4];
#pragma unroll
    for (int ni = 0; ni < 4; ni++) bb[ni] = biasf[n0 + nh * 64 + ni * 16 + lr];

    if (!out_f) {
        int region = nt >> 2;          // 0=q, 1=k(fp8), 2=v
        int col0 = (nt & 3) * 128;
        unsigned short* cs = smem;
#pragma unroll
        for (int g = 0; g < 4; g++) {
            __syncthreads();
            if (mh == (g >> 1)) {
                int miB = (g & 1) * 2;
#pragma unroll
                for (int m2 = 0; m2 < 2; m2++) {
                    int mi = miB + m2;
                    int lrow = mi * 16 + qd * 4 - (g & 1) * 32;
#pragma unroll
                    for (int ni = 0; ni < 4; ni++) {
                        int col = nh * 64 + ni * 16 + lr;
#pragma unroll
                        for (int r = 0; r < 4; r++)
                            cs[(lrow + r) * 128 + col] = f2bf(acc[mi][ni][r] + bb[ni]);
                    }
                }
            }
            __syncthreads();
#pragma unroll
            for (int itr = 0; itr < 2; itr++) {
                int slot = itr * 256 + tid;
                int row = slot >> 4, cg = slot & 15;
                int gm = m0 + g * 32 + row;
                if (gm < M) {
                    short8 vv = *(const short8*)(cs + row * 128 + cg * 8);
                    if (region == 1) {
                        union { short8 v; unsigned short u[8]; } pk; pk.v = vv;
                        int w0 = 0, w1 = 0;
                        w0 = __builtin_amdgcn_cvt_pk_fp8_f32(bf2f(pk.u[0]), bf2f(pk.u[1]), w0, false);
                        w0 = __builtin_amdgcn_cvt_pk_fp8_f32(bf2f(pk.u[2]), bf2f(pk.u[3]), w0, true);
                        w1 = __builtin_amdgcn_cvt_pk_fp8_f32(bf2f(pk.u[4]), bf2f(pk.u[5]), w1, false);
                        w1 = __builtin_amdgcn_cvt_pk_fp8_f32(bf2f(pk.u[6]), bf2f(pk.u[7]), w1, true);
                        uint2 o; o.x = (unsigned int)w0; o.y = (unsigned int)w1;
                        *(uint2*)(out_k8 + (size_t)gm * 512 + col0 + cg * 8) = o;
                    } else {
                        unsigned short* dp = (region == 0) ? out_q : out_v;
                        *(short8*)(dp + (size_t)gm * 512 + col0 + cg * 8) = vv;
                    }
                }
            }
        }
    } else {
#pragma unroll
        for (int ni = 0; ni < 4; ni++) {
            int gn = n0 + nh * 64 + ni * 16 + lr;
#pragma unroll
            for (int mi = 0; mi < 4; mi++) {
                int gm0 = m0 + mh * 64 + mi * 16 + qd * 4;
#pragma unroll
                for (int r = 0; r < 4; r++) {
                    int gm = gm0 + r;
                    if (gm < M) out_f[(size_t)gm * Ncols + gn] = acc[mi][ni][r] + bb[ni];
                }
            }
        }
    }
}

// ---------------- CSR build ---------------------------------------------------
__global__ void k_hist(const int* __restrict__ dst, int* __restrict__ counts) {
    int e = blockIdx.x * 256 + threadIdx.x;
    if (e < NE) atomicAdd(&counts[dst[e]], 1);
}

__global__ __launch_bounds__(1024) void k_scan(const int* __restrict__ counts,
                                               int* __restrict__ offsets,
                                               int* __restrict__ pos) {
    const int C = 20;
    __shared__ int wsum[16];
    __shared__ int wpre[16];
    int tid = threadIdx.x, lane = tid & 63, w = tid >> 6;
    int local[C];
    int run = 0;
#pragma unroll
    for (int i = 0; i < C; i++) {
        int idx = tid * C + i;
        int c = (idx < NND) ? counts[idx] : 0;
        local[i] = run; run += c;
    }
    int v = run;
#pragma unroll
    for (int off = 1; off < 64; off <<= 1) {
        int u = __shfl_up(v, off, 64);
        if (lane >= off) v += u;
    }
    if (lane == 63) wsum[w] = v;
    __syncthreads();
    if (tid == 0) { int acc = 0; for (int i = 0; i < 16; i++) { wpre[i] = acc; acc += wsum[i]; } }
    __syncthreads();
    int texcl = wpre[w] + (v - run);
#pragma unroll
    for (int i = 0; i < C; i++) {
        int idx = tid * C + i;
        if (idx < NND) { int o = texcl + local[i]; offsets[idx] = o; pos[idx] = o; }
    }
    if (tid == 1023) offsets[NND] = texcl + run;
}

__global__ void k_scatter(const int* __restrict__ dst, const int* __restrict__ src,
                          int* __restrict__ pos, int* __restrict__ ssrc) {
    int e = blockIdx.x * 256 + threadIdx.x;
    if (e < NE) { int p = atomicAdd(&pos[dst[e]], 1); ssrc[p] = src[e]; }
}

// ---------------- fused score+softmax+aggregate -------------------------------
// q: bf16 [N,512]; k: fp8 e4m3 [N,512] (x16; q carries /16); v: bf16 [N,512]
__global__ __launch_bounds__(256) void k_fsa(const int* __restrict__ offsets,
                                             const int* __restrict__ ssrc,
                                             const unsigned short* __restrict__ qb,
                                             const unsigned char* __restrict__ kf8,
                                             const unsigned short* __restrict__ vb,
                                             unsigned short* __restrict__ attn) {
    __shared__ float sacc[4][512];
    __shared__ float sden[4];
    int n = blockIdx.x, tid = threadIdx.x, wv = tid >> 6, ln = tid & 63;
    int beg = offsets[n], end = offsets[n + 1];
    union { short8 v; unsigned short u[8]; } qu;
    qu.v = *(const short8*)(qb + (size_t)n * 512 + ln * 8);
    float2v qf2[4];
#pragma unroll
    for (int j = 0; j < 4; j++) {
        qf2[j].x = bf2f(qu.u[2 * j]);
        qf2[j].y = bf2f(qu.u[2 * j + 1]);
    }
    float2v av2[4] = {{0,0},{0,0},{0,0},{0,0}};
    float den = 0.f;
    int i = beg + wv * 2;
    for (; i + 1 < end; i += 8) {
        int s0 = ssrc[i], s1 = ssrc[i + 1];
        uint2 kd0 = *(const uint2*)(kf8 + (size_t)s0 * 512 + ln * 8);
        uint2 kd1 = *(const uint2*)(kf8 + (size_t)s1 * 512 + ln * 8);
        float2v a0 = {0, 0}, a1 = {0, 0};
        float2v p;
        p = __builtin_amdgcn_cvt_pk_f32_fp8(kd0.x, false); a0 += qf2[0] * p;
        p = __builtin_amdgcn_cvt_pk_f32_fp8(kd0.x, true);  a0 += qf2[1] * p;
        p = __builtin_amdgcn_cvt_pk_f32_fp8(kd0.y, false); a0 += qf2[2] * p;
        p = __builtin_amdgcn_cvt_pk_f32_fp8(kd0.y, true);  a0 += qf2[3] * p;
        p = __builtin_amdgcn_cvt_pk_f32_fp8(kd1.x, false); a1 += qf2[0] * p;
        p = __builtin_amdgcn_cvt_pk_f32_fp8(kd1.x, true);  a1 += qf2[1] * p;
        p = __builtin_amdgcn_cvt_pk_f32_fp8(kd1.y, false); a1 += qf2[2] * p;
        p = __builtin_amdgcn_cvt_pk_f32_fp8(kd1.y, true);  a1 += qf2[3] * p;
        float d0 = a0.x + a0.y, d1 = a1.x + a1.y;
#pragma unroll
        for (int off = 32; off >= 1; off >>= 1) {
            d0 += __shfl_xor(d0, off, 64);
            d1 += __shfl_xor(d1, off, 64);
        }
        float w0 = __expf(d0), w1 = __expf(d1);
        den += w0 + w1;
        uint4 vd0 = *(const uint4*)(vb + (size_t)s0 * 512 + ln * 8);
        uint4 vd1 = *(const uint4*)(vb + (size_t)s1 * 512 + ln * 8);
        float2v w20 = {w0, w0}, w21 = {w1, w1};
        av2[0] += w20 * bfpair(vd0.x); av2[0] += w21 * bfpair(vd1.x);
        av2[1] += w20 * bfpair(vd0.y); av2[1] += w21 * bfpair(vd1.y);
        av2[2] += w20 * bfpair(vd0.z); av2[2] += w21 * bfpair(vd1.z);
        av2[3] += w20 * bfpair(vd0.w); av2[3] += w21 * bfpair(vd1.w);
    }
    if (i < end) {
        int s0 = ssrc[i];
        uint2 kd0 = *(const uint2*)(kf8 + (size_t)s0 * 512 + ln * 8);
        float2v a0 = {0, 0};
        float2v p;
        p = __builtin_amdgcn_cvt_pk_f32_fp8(kd0.x, false); a0 += qf2[0] * p;
        p = __builtin_amdgcn_cvt_pk_f32_fp8(kd0.x, true);  a0 += qf2[1] * p;
        p = __builtin_amdgcn_cvt_pk_f32_fp8(kd0.y, false); a0 += qf2[2] * p;
        p = __builtin_amdgcn_cvt_pk_f32_fp8(kd0.y, true);  a0 += qf2[3] * p;
        float d0 = a0.x + a0.y;
#pragma unroll
        for (int off = 32; off >= 1; off >>= 1) d0 += __shfl_xor(d0, off, 64);
        float w0 = __expf(d0);
        den += w0;
        uint4 vd0 = *(const uint4*)(vb + (size_t)s0 * 512 + ln * 8);
        float2v w20 = {w0, w0};
        av2[0] += w20 * bfpair(vd0.x);
        av2[1] += w20 * bfpair(vd0.y);
        av2[2] += w20 * bfpair(vd0.z);
        av2[3] += w20 * bfpair(vd0.w);
    }
    floatx4 s0v = {av2[0].x, av2[0].y, av2[1].x, av2[1].y};
    floatx4 s1v = {av2[2].x, av2[2].y, av2[3].x, av2[3].y};
    *(floatx4*)&sacc[wv][ln * 8]     = s0v;
    *(floatx4*)&sacc[wv][ln * 8 + 4] = s1v;
    if (ln == 0) sden[wv] = den;
    __syncthreads();
    float inv = 1.0f / (sden[0] + sden[1] + sden[2] + sden[3]);
    int c = tid * 2;
    float t0 = sacc[0][c] + sacc[1][c] + sacc[2][c] + sacc[3][c];
    float t1 = sacc[0][c + 1] + sacc[1][c + 1] + sacc[2][c + 1] + sacc[3][c + 1];
    attn[(size_t)n * 512 + c]     = f2bf(t0 * inv);
    attn[(size_t)n * 512 + c + 1] = f2bf(t1 * inv);
}

// ---------------- expmap0 in place --------------------------------------------
__global__ __launch_bounds__(64) void k_expmap(float* h) {
    int row = blockIdx.x, lane = threadIdx.x;
    floatx4* hp = (floatx4*)(h + (size_t)row * DIMK + lane * 8);
    floatx4 h0 = hp[0], h1 = hp[1];
    float ss = 0.f;
#pragma unroll
    for (int i = 0; i < 4; i++) { ss += h0[i] * h0[i]; ss += h1[i] * h1[i]; }
#pragma unroll
    for (int off = 32; off >= 1; off >>= 1) ss += __shfl_xor(ss, off, 64);
    float n  = sqrtf(ss);
    float nc = fmaxf(n, 1e-7f);
    float fac = tanhf(nc) / nc;
#pragma unroll
    for (int i = 0; i < 4; i++) { h0[i] *= fac; h1[i] *= fac; }
    hp[0] = h0; hp[1] = h1;
}

extern "C" void kernel_launch(void* const* d_in, const int* in_sizes, int n_in,
                              void* d_out, int out_size, void* d_ws, size_t ws_size,
                              hipStream_t stream) {
    const float* x  = (const float*)d_in[0];
    const int* src  = (const int*)d_in[1];
    const int* dst  = (const int*)d_in[2];
    const float* Wq = (const float*)d_in[3];
    const float* bq = (const float*)d_in[4];
    const float* Wk = (const float*)d_in[5];
    const float* bk = (const float*)d_in[6];
    const float* Wv = (const float*)d_in[7];
    const float* bv = (const float*)d_in[8];
    const float* Wo = (const float*)d_in[9];
    const float* bo = (const float*)d_in[10];
    float* out = (float*)d_out;

    char* ws = (char*)d_ws;
    const size_t RB = (size_t)NND * DIMK * 2;      // 20.48 MB bf16 [N,512]
    const size_t KB8 = (size_t)NND * DIMK;         // 10.24 MB fp8 [N,512]
    const size_t WB = (size_t)DIMK * DIMK * 2;
    unsigned short* t    = (unsigned short*)(ws);              // reused as attn
    unsigned short* qb   = (unsigned short*)(ws + RB);
    unsigned short* vb   = (unsigned short*)(ws + 2 * RB);
    unsigned char*  kf8  = (unsigned char*)(ws + 3 * RB);
    unsigned short* Wqkv = (unsigned short*)(ws + 3 * RB + KB8);
    unsigned short* Wob  = (unsigned short*)(ws + 3 * RB + KB8 + 3 * WB);
    float* biasf         = (float*)(ws + 3 * RB + KB8 + 4 * WB);
    char* p = ws + 3 * RB + KB8 + 4 * WB + 1536 * 4;
    int* ssrc    = (int*)p;
    int* counts  = ssrc + NE;
    int* offsets = counts + NND;
    int* pos     = offsets + NND + 2;
    unsigned short* attn = t;

    hipMemsetAsync(counts, 0, (size_t)NND * 4, stream);

    const float scale_q = 0.04419417382415922f / 16.0f;   // (1/sqrt(512)) / 16
    k_pre<<<6030, 256, 0, stream>>>(x, Wq, Wk, Wv, Wo, bq, bk, bv,
                                    t, Wqkv, Wob, biasf, scale_q);

    k_hist<<<(NE + 255) / 256, 256, 0, stream>>>(dst, counts);
    k_scan<<<1, 1024, 0, stream>>>(counts, offsets, pos);
    k_scatter<<<(NE + 255) / 256, 256, 0, stream>>>(dst, src, pos, ssrc);

    // fused q/k/v GEMM: [20000 x 1536] -> qb / kf8(x16) / vb
    k_gemm<<<8 * 20 * 12, 256, 0, stream>>>(t, Wqkv, biasf, qb, kf8, vb, nullptr,
                                            NND, 157, 12, 1536);

    k_fsa<<<NND, 256, 0, stream>>>(offsets, ssrc, qb, kf8, vb, attn);

    // output projection (fp32 into d_out), expmap in place
    k_gemm<<<8 * 20 * 4, 256, 0, stream>>>(attn, Wob, bo, nullptr, nullptr, nullptr, out,
                                           NND, 157, 4, 512);
    k_expmap<<<NND, 64, 0, stream>>>(out);
}

// Round 6
// 293.528 us; speedup vs baseline: 2.3619x; 1.0642x over previous
//
#include <hip/hip_runtime.h>
#include <math.h>
#include <stdint.h>

#define NND 20000
#define DIMK 512
#define NE  320000

typedef __attribute__((ext_vector_type(8))) short short8;
typedef __attribute__((ext_vector_type(4))) float floatx4;
typedef __attribute__((ext_vector_type(2))) float float2v;

__device__ inline float bf2f(unsigned short h) {
    unsigned int u = ((unsigned int)h) << 16;
    return __uint_as_float(u);
}
__device__ inline unsigned short f2bf(float f) {
    unsigned int u = __float_as_uint(f);
    unsigned int r = (u + 0x7fffu + ((u >> 16) & 1u)) >> 16;
    return (unsigned short)r;
}

__device__ __forceinline__ void gld_lds16(const unsigned short* g, unsigned short* l) {
    __builtin_amdgcn_global_load_lds(
        (const __attribute__((address_space(1))) void*)g,
        (__attribute__((address_space(3))) void*)l,
        16, 0, 0);
}

// ---------------- fused pre-pass: logmap + W cvt + bias + dst histogram -------
// blocks [0,5000): logmap (4 rows each); [5000,6024): W cvt; [6024,6030): bias;
// [6030,7280): histogram of dst
__global__ __launch_bounds__(256) void k_pre(const float* __restrict__ x,
                                             const float* __restrict__ Wq,
                                             const float* __restrict__ Wk,
                                             const float* __restrict__ Wv,
                                             const float* __restrict__ Wo,
                                             const float* __restrict__ bq,
                                             const float* __restrict__ bk,
                                             const float* __restrict__ bv,
                                             const int* __restrict__ dst,
                                             int* __restrict__ counts,
                                             unsigned short* __restrict__ t,
                                             unsigned short* __restrict__ Wqkv,
                                             unsigned short* __restrict__ Wob,
                                             float* __restrict__ biasf,
                                             float scale_q) {
    int blk = blockIdx.x, tid = threadIdx.x;
    if (blk < 5000) {
        int row = blk * 4 + (tid >> 6);
        int lane = tid & 63;
        const floatx4* xp = (const floatx4*)(x + (size_t)row * DIMK + lane * 8);
        floatx4 x0 = xp[0], x1 = xp[1];
        float ss = 0.f;
#pragma unroll
        for (int i = 0; i < 4; i++) { ss += x0[i] * x0[i]; ss += x1[i] * x1[i]; }
#pragma unroll
        for (int off = 32; off >= 1; off >>= 1) ss += __shfl_xor(ss, off, 64);
        float n  = sqrtf(ss);
        float nc = fminf(fmaxf(n, 1e-7f), 1.0f - 1e-6f);
        float fac = atanhf(nc) / nc;
        union { short8 v; unsigned short u[8]; } o;
#pragma unroll
        for (int i = 0; i < 4; i++) { o.u[i] = f2bf(fac * x0[i]); o.u[4 + i] = f2bf(fac * x1[i]); }
        *(short8*)(t + (size_t)row * DIMK + lane * 8) = o.v;
    } else if (blk < 6024) {
        int i = (blk - 5000) * 256 + tid;           // 0 .. 4*65536
        int m = i >> 16, j = i & 65535;
        const float* in; unsigned short* out; float sc = 1.0f;
        if (m == 0)      { in = Wq; out = Wqkv;               sc = scale_q; }
        else if (m == 1) { in = Wk; out = Wqkv + 512 * DIMK;  sc = 16.0f; }
        else if (m == 2) { in = Wv; out = Wqkv + 1024 * DIMK; sc = 16.0f; }
        else             { in = Wo; out = Wob; }
        floatx4 f = *(const floatx4*)(in + (size_t)j * 4);
        union { unsigned long long d; unsigned short u[4]; } o;
#pragma unroll
        for (int q = 0; q < 4; q++) o.u[q] = f2bf(f[q] * sc);
        *(unsigned long long*)(out + (size_t)j * 4) = o.d;
    } else if (blk < 6030) {
        int i = (blk - 6024) * 256 + tid;           // 0..1535
        if (i < 512) biasf[i] = bq[i] * scale_q;
        else if (i < 1024) biasf[i] = bk[i - 512] * 16.0f;
        else if (i < 1536) biasf[i] = bv[i - 1024] * 16.0f;
    } else {
        int e = (blk - 6030) * 256 + tid;
        if (e < NE) atomicAdd(&counts[dst[e]], 1);
    }
}

// ---------------- double-buffered GEMM, 128x128, BK=32, XCD swizzle -----------
// qkv mode (out_f==0): nt 0-3 -> q bf16; nt 4-7 -> k fp8 (x16); nt 8-11 -> v fp8 (x16)
//   k/v interleave into kv8 rows: [k(512B) | v(512B)], stride 1024.
// proj mode (out_f!=0): direct fp32 stores
__global__ __launch_bounds__(256) void k_gemm(const unsigned short* __restrict__ A,
                                              const unsigned short* __restrict__ B,
                                              const float* __restrict__ biasf,
                                              unsigned short* __restrict__ out_q,
                                              unsigned char*  __restrict__ out_kv8,
                                              float* __restrict__ out_f,
                                              int M, int MT, int NT, int Ncols) {
    __shared__ unsigned short smem[16384];
    int b = blockIdx.x;
    int xcd = b & 7, i = b >> 3;
    int nt = i % NT, mt = (i / NT) * 8 + xcd;
    if (mt >= MT) return;
    int m0 = mt * 128, n0 = nt * 128;
    int tid = threadIdx.x, wv = tid >> 6, ln = tid & 63;
    int lr = ln & 15, qd = ln >> 4;
    int mh = wv >> 1, nh = wv & 1;

    floatx4 acc[4][4] = {};
    int srow = wv * 16 + (ln >> 2);
    int scol = (ln & 3) * 8;

    {
        unsigned short* Ab = smem;
        unsigned short* Bb = smem + 8192;
#pragma unroll
        for (int p = 0; p < 2; p++) {
            int tr = p * 64 + srow;
            int ar = m0 + tr; if (ar > M - 1) ar = M - 1;
            gld_lds16(A + (size_t)ar * DIMK + scol, Ab + (p * 64 + wv * 16) * 32);
            gld_lds16(B + (size_t)(n0 + tr) * DIMK + scol, Bb + (p * 64 + wv * 16) * 32);
        }
    }

    for (int it = 0; it < 16; it++) {
        int cur = it & 1, nxt = cur ^ 1;
        __syncthreads();
        if (it + 1 < 16) {
            int kb = (it + 1) * 32;
            unsigned short* Ab = smem + nxt * 4096;
            unsigned short* Bb = smem + 8192 + nxt * 4096;
#pragma unroll
            for (int p = 0; p < 2; p++) {
                int tr = p * 64 + srow;
                int ar = m0 + tr; if (ar > M - 1) ar = M - 1;
                gld_lds16(A + (size_t)ar * DIMK + kb + scol, Ab + (p * 64 + wv * 16) * 32);
                gld_lds16(B + (size_t)(n0 + tr) * DIMK + kb + scol, Bb + (p * 64 + wv * 16) * 32);
            }
        }
        const unsigned short* Ac = smem + cur * 4096;
        const unsigned short* Bc = smem + 8192 + cur * 4096;
        short8 af[4], bfr[4];
#pragma unroll
        for (int mi = 0; mi < 4; mi++)
            af[mi] = *(const short8*)(Ac + (mh * 64 + mi * 16 + lr) * 32 + qd * 8);
#pragma unroll
        for (int ni = 0; ni < 4; ni++)
            bfr[ni] = *(const short8*)(Bc + (nh * 64 + ni * 16 + lr) * 32 + qd * 8);
#pragma unroll
        for (int mi = 0; mi < 4; mi++)
#pragma unroll
            for (int ni = 0; ni < 4; ni++)
                acc[mi][ni] = __builtin_amdgcn_mfma_f32_16x16x32_bf16(af[mi], bfr[ni], acc[mi][ni], 0, 0, 0);
    }

    float bb[4];
#pragma unroll
    for (int ni = 0; ni < 4; ni++) bb[ni] = biasf[n0 + nh * 64 + ni * 16 + lr];

    if (!out_f) {
        int region = nt >> 2;          // 0=q bf16, 1=k fp8, 2=v fp8
        int col0 = (nt & 3) * 128;
        unsigned short* cs = smem;
#pragma unroll
        for (int g = 0; g < 4; g++) {
            __syncthreads();
            if (mh == (g >> 1)) {
                int miB = (g & 1) * 2;
#pragma unroll
                for (int m2 = 0; m2 < 2; m2++) {
                    int mi = miB + m2;
                    int lrow = mi * 16 + qd * 4 - (g & 1) * 32;
#pragma unroll
                    for (int ni = 0; ni < 4; ni++) {
                        int col = nh * 64 + ni * 16 + lr;
#pragma unroll
                        for (int r = 0; r < 4; r++)
                            cs[(lrow + r) * 128 + col] = f2bf(acc[mi][ni][r] + bb[ni]);
                    }
                }
            }
            __syncthreads();
#pragma unroll
            for (int itr = 0; itr < 2; itr++) {
                int slot = itr * 256 + tid;
                int row = slot >> 4, cg = slot & 15;
                int gm = m0 + g * 32 + row;
                if (gm < M) {
                    short8 vv = *(const short8*)(cs + row * 128 + cg * 8);
                    if (region == 0) {
                        *(short8*)(out_q + (size_t)gm * 512 + col0 + cg * 8) = vv;
                    } else {
                        union { short8 v; unsigned short u[8]; } pk; pk.v = vv;
                        int w0 = 0, w1 = 0;
                        w0 = __builtin_amdgcn_cvt_pk_fp8_f32(bf2f(pk.u[0]), bf2f(pk.u[1]), w0, false);
                        w0 = __builtin_amdgcn_cvt_pk_fp8_f32(bf2f(pk.u[2]), bf2f(pk.u[3]), w0, true);
                        w1 = __builtin_amdgcn_cvt_pk_fp8_f32(bf2f(pk.u[4]), bf2f(pk.u[5]), w1, false);
                        w1 = __builtin_amdgcn_cvt_pk_fp8_f32(bf2f(pk.u[6]), bf2f(pk.u[7]), w1, true);
                        uint2 o; o.x = (unsigned int)w0; o.y = (unsigned int)w1;
                        size_t off = (size_t)gm * 1024 + (region == 2 ? 512 : 0) + col0 + cg * 8;
                        *(uint2*)(out_kv8 + off) = o;
                    }
                }
            }
        }
    } else {
#pragma unroll
        for (int ni = 0; ni < 4; ni++) {
            int gn = n0 + nh * 64 + ni * 16 + lr;
#pragma unroll
            for (int mi = 0; mi < 4; mi++) {
                int gm0 = m0 + mh * 64 + mi * 16 + qd * 4;
#pragma unroll
                for (int r = 0; r < 4; r++) {
                    int gm = gm0 + r;
                    if (gm < M) out_f[(size_t)gm * Ncols + gn] = acc[mi][ni][r] + bb[ni];
                }
            }
        }
    }
}

// ---------------- CSR scan + scatter ------------------------------------------
__global__ __launch_bounds__(1024) void k_scan(const int* __restrict__ counts,
                                               int* __restrict__ offsets,
                                               int* __restrict__ pos) {
    const int C = 20;
    __shared__ int wsum[16];
    __shared__ int wpre[16];
    int tid = threadIdx.x, lane = tid & 63, w = tid >> 6;
    int local[C];
    int run = 0;
#pragma unroll
    for (int i = 0; i < C; i++) {
        int idx = tid * C + i;
        int c = (idx < NND) ? counts[idx] : 0;
        local[i] = run; run += c;
    }
    int v = run;
#pragma unroll
    for (int off = 1; off < 64; off <<= 1) {
        int u = __shfl_up(v, off, 64);
        if (lane >= off) v += u;
    }
    if (lane == 63) wsum[w] = v;
    __syncthreads();
    if (tid == 0) { int acc = 0; for (int i = 0; i < 16; i++) { wpre[i] = acc; acc += wsum[i]; } }
    __syncthreads();
    int texcl = wpre[w] + (v - run);
#pragma unroll
    for (int i = 0; i < C; i++) {
        int idx = tid * C + i;
        if (idx < NND) { int o = texcl + local[i]; offsets[idx] = o; pos[idx] = o; }
    }
    if (tid == 1023) offsets[NND] = texcl + run;
}

__global__ void k_scatter(const int* __restrict__ dst, const int* __restrict__ src,
                          int* __restrict__ pos, int* __restrict__ ssrc) {
    int e = blockIdx.x * 256 + threadIdx.x;
    if (e < NE) { int p = atomicAdd(&pos[dst[e]], 1); ssrc[p] = src[e]; }
}

// ---------------- fused score+softmax+aggregate -------------------------------
// q: bf16 [N,512] (carries /(16*sqrt(d))); kv8: fp8 e4m3 [N, k(512)|v(512)] (x16)
__global__ __launch_bounds__(256) void k_fsa(const int* __restrict__ offsets,
                                             const int* __restrict__ ssrc,
                                             const unsigned short* __restrict__ qb,
                                             const unsigned char* __restrict__ kv8,
                                             unsigned short* __restrict__ attn) {
    __shared__ float sacc[4][512];
    __shared__ float sden[4];
    int n = blockIdx.x, tid = threadIdx.x, wv = tid >> 6, ln = tid & 63;
    int beg = offsets[n], end = offsets[n + 1];
    union { short8 v; unsigned short u[8]; } qu;
    qu.v = *(const short8*)(qb + (size_t)n * 512 + ln * 8);
    float2v qf2[4];
#pragma unroll
    for (int j = 0; j < 4; j++) {
        qf2[j].x = bf2f(qu.u[2 * j]);
        qf2[j].y = bf2f(qu.u[2 * j + 1]);
    }
    float2v av2[4] = {{0,0},{0,0},{0,0},{0,0}};
    float den = 0.f;
    int i = beg + wv * 2;
    for (; i + 1 < end; i += 8) {
        const unsigned char* p0 = kv8 + (size_t)ssrc[i] * 1024 + ln * 8;
        const unsigned char* p1 = kv8 + (size_t)ssrc[i + 1] * 1024 + ln * 8;
        uint2 kd0 = *(const uint2*)p0;
        uint2 kd1 = *(const uint2*)p1;
        float2v a0 = {0, 0}, a1 = {0, 0};
        float2v p;
        p = __builtin_amdgcn_cvt_pk_f32_fp8(kd0.x, false); a0 += qf2[0] * p;
        p = __builtin_amdgcn_cvt_pk_f32_fp8(kd0.x, true);  a0 += qf2[1] * p;
        p = __builtin_amdgcn_cvt_pk_f32_fp8(kd0.y, false); a0 += qf2[2] * p;
        p = __builtin_amdgcn_cvt_pk_f32_fp8(kd0.y, true);  a0 += qf2[3] * p;
        p = __builtin_amdgcn_cvt_pk_f32_fp8(kd1.x, false); a1 += qf2[0] * p;
        p = __builtin_amdgcn_cvt_pk_f32_fp8(kd1.x, true);  a1 += qf2[1] * p;
        p = __builtin_amdgcn_cvt_pk_f32_fp8(kd1.y, false); a1 += qf2[2] * p;
        p = __builtin_amdgcn_cvt_pk_f32_fp8(kd1.y, true);  a1 += qf2[3] * p;
        float d0 = a0.x + a0.y, d1 = a1.x + a1.y;
#pragma unroll
        for (int off = 32; off >= 1; off >>= 1) {
            d0 += __shfl_xor(d0, off, 64);
            d1 += __shfl_xor(d1, off, 64);
        }
        float w0 = __expf(d0), w1 = __expf(d1);
        den += w0 + w1;
        uint2 vd0 = *(const uint2*)(p0 + 512);
        uint2 vd1 = *(const uint2*)(p1 + 512);
        float2v w20 = {w0, w0}, w21 = {w1, w1};
        p = __builtin_amdgcn_cvt_pk_f32_fp8(vd0.x, false); av2[0] += w20 * p;
        p = __builtin_amdgcn_cvt_pk_f32_fp8(vd0.x, true);  av2[1] += w20 * p;
        p = __builtin_amdgcn_cvt_pk_f32_fp8(vd0.y, false); av2[2] += w20 * p;
        p = __builtin_amdgcn_cvt_pk_f32_fp8(vd0.y, true);  av2[3] += w20 * p;
        p = __builtin_amdgcn_cvt_pk_f32_fp8(vd1.x, false); av2[0] += w21 * p;
        p = __builtin_amdgcn_cvt_pk_f32_fp8(vd1.x, true);  av2[1] += w21 * p;
        p = __builtin_amdgcn_cvt_pk_f32_fp8(vd1.y, false); av2[2] += w21 * p;
        p = __builtin_amdgcn_cvt_pk_f32_fp8(vd1.y, true);  av2[3] += w21 * p;
    }
    if (i < end) {
        const unsigned char* p0 = kv8 + (size_t)ssrc[i] * 1024 + ln * 8;
        uint2 kd0 = *(const uint2*)p0;
        float2v a0 = {0, 0};
        float2v p;
        p = __builtin_amdgcn_cvt_pk_f32_fp8(kd0.x, false); a0 += qf2[0] * p;
        p = __builtin_amdgcn_cvt_pk_f32_fp8(kd0.x, true);  a0 += qf2[1] * p;
        p = __builtin_amdgcn_cvt_pk_f32_fp8(kd0.y, false); a0 += qf2[2] * p;
        p = __builtin_amdgcn_cvt_pk_f32_fp8(kd0.y, true);  a0 += qf2[3] * p;
        float d0 = a0.x + a0.y;
#pragma unroll
        for (int off = 32; off >= 1; off >>= 1) d0 += __shfl_xor(d0, off, 64);
        float w0 = __expf(d0);
        den += w0;
        uint2 vd0 = *(const uint2*)(p0 + 512);
        float2v w20 = {w0, w0};
        p = __builtin_amdgcn_cvt_pk_f32_fp8(vd0.x, false); av2[0] += w20 * p;
        p = __builtin_amdgcn_cvt_pk_f32_fp8(vd0.x, true);  av2[1] += w20 * p;
        p = __builtin_amdgcn_cvt_pk_f32_fp8(vd0.y, false); av2[2] += w20 * p;
        p = __builtin_amdgcn_cvt_pk_f32_fp8(vd0.y, true);  av2[3] += w20 * p;
    }
    floatx4 s0v = {av2[0].x, av2[0].y, av2[1].x, av2[1].y};
    floatx4 s1v = {av2[2].x, av2[2].y, av2[3].x, av2[3].y};
    *(floatx4*)&sacc[wv][ln * 8]     = s0v;
    *(floatx4*)&sacc[wv][ln * 8 + 4] = s1v;
    if (ln == 0) sden[wv] = den;
    __syncthreads();
    // 0.0625 undoes the x16 fold on v
    float inv = 0.0625f / (sden[0] + sden[1] + sden[2] + sden[3]);
    int c = tid * 2;
    float t0 = sacc[0][c] + sacc[1][c] + sacc[2][c] + sacc[3][c];
    float t1 = sacc[0][c + 1] + sacc[1][c + 1] + sacc[2][c + 1] + sacc[3][c + 1];
    attn[(size_t)n * 512 + c]     = f2bf(t0 * inv);
    attn[(size_t)n * 512 + c + 1] = f2bf(t1 * inv);
}

// ---------------- expmap0 in place --------------------------------------------
__global__ __launch_bounds__(64) void k_expmap(float* h) {
    int row = blockIdx.x, lane = threadIdx.x;
    floatx4* hp = (floatx4*)(h + (size_t)row * DIMK + lane * 8);
    floatx4 h0 = hp[0], h1 = hp[1];
    float ss = 0.f;
#pragma unroll
    for (int i = 0; i < 4; i++) { ss += h0[i] * h0[i]; ss += h1[i] * h1[i]; }
#pragma unroll
    for (int off = 32; off >= 1; off >>= 1) ss += __shfl_xor(ss, off, 64);
    float n  = sqrtf(ss);
    float nc = fmaxf(n, 1e-7f);
    float fac = tanhf(nc) / nc;
#pragma unroll
    for (int i = 0; i < 4; i++) { h0[i] *= fac; h1[i] *= fac; }
    hp[0] = h0; hp[1] = h1;
}

extern "C" void kernel_launch(void* const* d_in, const int* in_sizes, int n_in,
                              void* d_out, int out_size, void* d_ws, size_t ws_size,
                              hipStream_t stream) {
    const float* x  = (const float*)d_in[0];
    const int* src  = (const int*)d_in[1];
    const int* dst  = (const int*)d_in[2];
    const float* Wq = (const float*)d_in[3];
    const float* bq = (const float*)d_in[4];
    const float* Wk = (const float*)d_in[5];
    const float* bk = (const float*)d_in[6];
    const float* Wv = (const float*)d_in[7];
    const float* bv = (const float*)d_in[8];
    const float* Wo = (const float*)d_in[9];
    const float* bo = (const float*)d_in[10];
    float* out = (float*)d_out;

    char* ws = (char*)d_ws;
    const size_t RB = (size_t)NND * DIMK * 2;      // 20.48 MB bf16 [N,512]
    const size_t KVB = (size_t)NND * 1024;         // 20.48 MB fp8 [N, k|v]
    const size_t WB = (size_t)DIMK * DIMK * 2;
    unsigned short* t    = (unsigned short*)(ws);              // reused as attn
    unsigned short* qb   = (unsigned short*)(ws + RB);
    unsigned char*  kv8  = (unsigned char*)(ws + 2 * RB);
    unsigned short* Wqkv = (unsigned short*)(ws + 2 * RB + KVB);
    unsigned short* Wob  = (unsigned short*)(ws + 2 * RB + KVB + 3 * WB);
    float* biasf         = (float*)(ws + 2 * RB + KVB + 4 * WB);
    char* p = ws + 2 * RB + KVB + 4 * WB + 1536 * 4;
    int* ssrc    = (int*)p;
    int* counts  = ssrc + NE;
    int* offsets = counts + NND;
    int* pos     = offsets + NND + 2;
    unsigned short* attn = t;

    hipMemsetAsync(counts, 0, (size_t)NND * 4, stream);

    const float scale_q = 0.04419417382415922f / 16.0f;   // (1/sqrt(512)) / 16
    k_pre<<<7280, 256, 0, stream>>>(x, Wq, Wk, Wv, Wo, bq, bk, bv, dst, counts,
                                    t, Wqkv, Wob, biasf, scale_q);

    k_scan<<<1, 1024, 0, stream>>>(counts, offsets, pos);
    k_scatter<<<(NE + 255) / 256, 256, 0, stream>>>(dst, src, pos, ssrc);

    // fused q/k/v GEMM: [20000 x 1536] -> qb bf16 / kv8 fp8 (k|v interleaved)
    k_gemm<<<8 * 20 * 12, 256, 0, stream>>>(t, Wqkv, biasf, qb, kv8, nullptr,
                                            NND, 157, 12, 1536);

    k_fsa<<<NND, 256, 0, stream>>>(offsets, ssrc, qb, kv8, attn);

    // output projection (fp32 into d_out), expmap in place
    k_gemm<<<8 * 20 * 4, 256, 0, stream>>>(attn, Wob, bo, nullptr, nullptr, out,
                                           NND, 157, 4, 512);
    k_expmap<<<NND, 64, 0, stream>>>(out);
}

// Round 7
// 289.629 us; speedup vs baseline: 2.3937x; 1.0135x over previous
//
#include <hip/hip_runtime.h>
#include <math.h>
#include <stdint.h>

#define NND 20000
#define DIMK 512
#define NE  320000

typedef __attribute__((ext_vector_type(8))) short short8;
typedef __attribute__((ext_vector_type(4))) float floatx4;
typedef __attribute__((ext_vector_type(2))) float float2v;

__device__ inline float bf2f(unsigned short h) {
    unsigned int u = ((unsigned int)h) << 16;
    return __uint_as_float(u);
}
__device__ inline unsigned short f2bf(float f) {
    unsigned int u = __float_as_uint(f);
    unsigned int r = (u + 0x7fffu + ((u >> 16) & 1u)) >> 16;
    return (unsigned short)r;
}

__device__ __forceinline__ void gld_lds16(const unsigned short* g, unsigned short* l) {
    __builtin_amdgcn_global_load_lds(
        (const __attribute__((address_space(1))) void*)g,
        (__attribute__((address_space(3))) void*)l,
        16, 0, 0);
}

// ---------------- fused pre-pass: logmap + W cvt + bias + dst histogram -------
// blocks [0,5000): logmap (4 rows each); [5000,6024): W cvt; [6024,6030): bias;
// [6030,7280): histogram of dst
__global__ __launch_bounds__(256) void k_pre(const float* __restrict__ x,
                                             const float* __restrict__ Wq,
                                             const float* __restrict__ Wk,
                                             const float* __restrict__ Wv,
                                             const float* __restrict__ Wo,
                                             const float* __restrict__ bq,
                                             const float* __restrict__ bk,
                                             const float* __restrict__ bv,
                                             const int* __restrict__ dst,
                                             int* __restrict__ counts,
                                             unsigned short* __restrict__ t,
                                             unsigned short* __restrict__ Wqkv,
                                             unsigned short* __restrict__ Wob,
                                             float* __restrict__ biasf,
                                             float scale_q) {
    int blk = blockIdx.x, tid = threadIdx.x;
    if (blk < 5000) {
        int row = blk * 4 + (tid >> 6);
        int lane = tid & 63;
        const floatx4* xp = (const floatx4*)(x + (size_t)row * DIMK + lane * 8);
        floatx4 x0 = xp[0], x1 = xp[1];
        float ss = 0.f;
#pragma unroll
        for (int i = 0; i < 4; i++) { ss += x0[i] * x0[i]; ss += x1[i] * x1[i]; }
#pragma unroll
        for (int off = 32; off >= 1; off >>= 1) ss += __shfl_xor(ss, off, 64);
        float n  = sqrtf(ss);
        float nc = fminf(fmaxf(n, 1e-7f), 1.0f - 1e-6f);
        float fac = atanhf(nc) / nc;
        union { short8 v; unsigned short u[8]; } o;
#pragma unroll
        for (int i = 0; i < 4; i++) { o.u[i] = f2bf(fac * x0[i]); o.u[4 + i] = f2bf(fac * x1[i]); }
        *(short8*)(t + (size_t)row * DIMK + lane * 8) = o.v;
    } else if (blk < 6024) {
        int i = (blk - 5000) * 256 + tid;           // 0 .. 4*65536
        int m = i >> 16, j = i & 65535;
        const float* in; unsigned short* out; float sc = 1.0f;
        if (m == 0)      { in = Wq; out = Wqkv;               sc = scale_q; }
        else if (m == 1) { in = Wk; out = Wqkv + 512 * DIMK;  sc = 16.0f; }
        else if (m == 2) { in = Wv; out = Wqkv + 1024 * DIMK; sc = 16.0f; }
        else             { in = Wo; out = Wob; }
        floatx4 f = *(const floatx4*)(in + (size_t)j * 4);
        union { unsigned long long d; unsigned short u[4]; } o;
#pragma unroll
        for (int q = 0; q < 4; q++) o.u[q] = f2bf(f[q] * sc);
        *(unsigned long long*)(out + (size_t)j * 4) = o.d;
    } else if (blk < 6030) {
        int i = (blk - 6024) * 256 + tid;           // 0..1535
        if (i < 512) biasf[i] = bq[i] * scale_q;
        else if (i < 1024) biasf[i] = bk[i - 512] * 16.0f;
        else if (i < 1536) biasf[i] = bv[i - 1024] * 16.0f;
    } else {
        int e = (blk - 6030) * 256 + tid;
        if (e < NE) atomicAdd(&counts[dst[e]], 1);
    }
}

// ---------------- double-buffered GEMM, 128x128, BK=32, XCD swizzle -----------
// LDS bank-conflict fix: staging lane ln sources k-group (ln&3)^(ln>>4) so the
// contiguous-dest global_load_lds produces an XOR-swizzled layout; fragment
// reads at (qd ^ (lr>>2)) then hit each 16B bank-group exactly 2x per phase
// (2-way = free, vs 8-way before). Bitwise-identical math.
// qkv mode (out_f==0): nt 0-3 -> q bf16; nt 4-7 -> k fp8 (x16); nt 8-11 -> v fp8 (x16)
//   k/v interleave into kv8 rows: [k(512B) | v(512B)], stride 1024.
// proj mode (out_f!=0): direct fp32 stores
__global__ __launch_bounds__(256) void k_gemm(const unsigned short* __restrict__ A,
                                              const unsigned short* __restrict__ B,
                                              const float* __restrict__ biasf,
                                              unsigned short* __restrict__ out_q,
                                              unsigned char*  __restrict__ out_kv8,
                                              float* __restrict__ out_f,
                                              int M, int MT, int NT, int Ncols) {
    __shared__ unsigned short smem[16384];
    int b = blockIdx.x;
    int xcd = b & 7, i = b >> 3;
    int nt = i % NT, mt = (i / NT) * 8 + xcd;
    if (mt >= MT) return;
    int m0 = mt * 128, n0 = nt * 128;
    int tid = threadIdx.x, wv = tid >> 6, ln = tid & 63;
    int lr = ln & 15, qd = ln >> 4;
    int mh = wv >> 1, nh = wv & 1;

    floatx4 acc[4][4] = {};
    int srow = wv * 16 + (ln >> 2);
    int scol = (((ln & 3) ^ (ln >> 4)) & 3) * 8;     // XOR-swizzled source k-group
    int fsw = (qd ^ (lr >> 2)) & 3;                  // fragment-read swizzle

    {
        unsigned short* Ab = smem;
        unsigned short* Bb = smem + 8192;
#pragma unroll
        for (int p = 0; p < 2; p++) {
            int tr = p * 64 + srow;
            int ar = m0 + tr; if (ar > M - 1) ar = M - 1;
            gld_lds16(A + (size_t)ar * DIMK + scol, Ab + (p * 64 + wv * 16) * 32);
            gld_lds16(B + (size_t)(n0 + tr) * DIMK + scol, Bb + (p * 64 + wv * 16) * 32);
        }
    }

    for (int it = 0; it < 16; it++) {
        int cur = it & 1, nxt = cur ^ 1;
        __syncthreads();
        if (it + 1 < 16) {
            int kb = (it + 1) * 32;
            unsigned short* Ab = smem + nxt * 4096;
            unsigned short* Bb = smem + 8192 + nxt * 4096;
#pragma unroll
            for (int p = 0; p < 2; p++) {
                int tr = p * 64 + srow;
                int ar = m0 + tr; if (ar > M - 1) ar = M - 1;
                gld_lds16(A + (size_t)ar * DIMK + kb + scol, Ab + (p * 64 + wv * 16) * 32);
                gld_lds16(B + (size_t)(n0 + tr) * DIMK + kb + scol, Bb + (p * 64 + wv * 16) * 32);
            }
        }
        const unsigned short* Ac = smem + cur * 4096;
        const unsigned short* Bc = smem + 8192 + cur * 4096;
        short8 af[4], bfr[4];
#pragma unroll
        for (int mi = 0; mi < 4; mi++)
            af[mi] = *(const short8*)(Ac + (mh * 64 + mi * 16 + lr) * 32 + fsw * 8);
#pragma unroll
        for (int ni = 0; ni < 4; ni++)
            bfr[ni] = *(const short8*)(Bc + (nh * 64 + ni * 16 + lr) * 32 + fsw * 8);
#pragma unroll
        for (int mi = 0; mi < 4; mi++)
#pragma unroll
            for (int ni = 0; ni < 4; ni++)
                acc[mi][ni] = __builtin_amdgcn_mfma_f32_16x16x32_bf16(af[mi], bfr[ni], acc[mi][ni], 0, 0, 0);
    }

    float bb[4];
#pragma unroll
    for (int ni = 0; ni < 4; ni++) bb[ni] = biasf[n0 + nh * 64 + ni * 16 + lr];

    if (!out_f) {
        int region = nt >> 2;          // 0=q bf16, 1=k fp8, 2=v fp8
        int col0 = (nt & 3) * 128;
        unsigned short* cs = smem;
#pragma unroll
        for (int g = 0; g < 4; g++) {
            __syncthreads();
            if (mh == (g >> 1)) {
                int miB = (g & 1) * 2;
#pragma unroll
                for (int m2 = 0; m2 < 2; m2++) {
                    int mi = miB + m2;
                    int lrow = mi * 16 + qd * 4 - (g & 1) * 32;
#pragma unroll
                    for (int ni = 0; ni < 4; ni++) {
                        int col = nh * 64 + ni * 16 + lr;
#pragma unroll
                        for (int r = 0; r < 4; r++)
                            cs[(lrow + r) * 128 + col] = f2bf(acc[mi][ni][r] + bb[ni]);
                    }
                }
            }
            __syncthreads();
#pragma unroll
            for (int itr = 0; itr < 2; itr++) {
                int slot = itr * 256 + tid;
                int row = slot >> 4, cg = slot & 15;
                int gm = m0 + g * 32 + row;
                if (gm < M) {
                    short8 vv = *(const short8*)(cs + row * 128 + cg * 8);
                    if (region == 0) {
                        *(short8*)(out_q + (size_t)gm * 512 + col0 + cg * 8) = vv;
                    } else {
                        union { short8 v; unsigned short u[8]; } pk; pk.v = vv;
                        int w0 = 0, w1 = 0;
                        w0 = __builtin_amdgcn_cvt_pk_fp8_f32(bf2f(pk.u[0]), bf2f(pk.u[1]), w0, false);
                        w0 = __builtin_amdgcn_cvt_pk_fp8_f32(bf2f(pk.u[2]), bf2f(pk.u[3]), w0, true);
                        w1 = __builtin_amdgcn_cvt_pk_fp8_f32(bf2f(pk.u[4]), bf2f(pk.u[5]), w1, false);
                        w1 = __builtin_amdgcn_cvt_pk_fp8_f32(bf2f(pk.u[6]), bf2f(pk.u[7]), w1, true);
                        uint2 o; o.x = (unsigned int)w0; o.y = (unsigned int)w1;
                        size_t off = (size_t)gm * 1024 + (region == 2 ? 512 : 0) + col0 + cg * 8;
                        *(uint2*)(out_kv8 + off) = o;
                    }
                }
            }
        }
    } else {
#pragma unroll
        for (int ni = 0; ni < 4; ni++) {
            int gn = n0 + nh * 64 + ni * 16 + lr;
#pragma unroll
            for (int mi = 0; mi < 4; mi++) {
                int gm0 = m0 + mh * 64 + mi * 16 + qd * 4;
#pragma unroll
                for (int r = 0; r < 4; r++) {
                    int gm = gm0 + r;
                    if (gm < M) out_f[(size_t)gm * Ncols + gn] = acc[mi][ni][r] + bb[ni];
                }
            }
        }
    }
}

// ---------------- CSR scan + scatter ------------------------------------------
__global__ __launch_bounds__(1024) void k_scan(const int* __restrict__ counts,
                                               int* __restrict__ offsets,
                                               int* __restrict__ pos) {
    const int C = 20;
    __shared__ int wsum[16];
    __shared__ int wpre[16];
    int tid = threadIdx.x, lane = tid & 63, w = tid >> 6;
    int local[C];
    int run = 0;
#pragma unroll
    for (int i = 0; i < C; i++) {
        int idx = tid * C + i;
        int c = (idx < NND) ? counts[idx] : 0;
        local[i] = run; run += c;
    }
    int v = run;
#pragma unroll
    for (int off = 1; off < 64; off <<= 1) {
        int u = __shfl_up(v, off, 64);
        if (lane >= off) v += u;
    }
    if (lane == 63) wsum[w] = v;
    __syncthreads();
    if (tid == 0) { int acc = 0; for (int i = 0; i < 16; i++) { wpre[i] = acc; acc += wsum[i]; } }
    __syncthreads();
    int texcl = wpre[w] + (v - run);
#pragma unroll
    for (int i = 0; i < C; i++) {
        int idx = tid * C + i;
        if (idx < NND) { int o = texcl + local[i]; offsets[idx] = o; pos[idx] = o; }
    }
    if (tid == 1023) offsets[NND] = texcl + run;
}

__global__ void k_scatter(const int* __restrict__ dst, const int* __restrict__ src,
                          int* __restrict__ pos, int* __restrict__ ssrc) {
    int e = blockIdx.x * 256 + threadIdx.x;
    if (e < NE) { int p = atomicAdd(&pos[dst[e]], 1); ssrc[p] = src[e]; }
}

// ---------------- fused score+softmax+aggregate -------------------------------
// q: bf16 [N,512] (carries /(16*sqrt(d))); kv8: fp8 e4m3 [N, k(512)|v(512)] (x16)
__global__ __launch_bounds__(256) void k_fsa(const int* __restrict__ offsets,
                                             const int* __restrict__ ssrc,
                                             const unsigned short* __restrict__ qb,
                                             const unsigned char* __restrict__ kv8,
                                             unsigned short* __restrict__ attn) {
    __shared__ float sacc[4][512];
    __shared__ float sden[4];
    int n = blockIdx.x, tid = threadIdx.x, wv = tid >> 6, ln = tid & 63;
    int beg = offsets[n], end = offsets[n + 1];
    union { short8 v; unsigned short u[8]; } qu;
    qu.v = *(const short8*)(qb + (size_t)n * 512 + ln * 8);
    float2v qf2[4];
#pragma unroll
    for (int j = 0; j < 4; j++) {
        qf2[j].x = bf2f(qu.u[2 * j]);
        qf2[j].y = bf2f(qu.u[2 * j + 1]);
    }
    float2v av2[4] = {{0,0},{0,0},{0,0},{0,0}};
    float den = 0.f;
    int i = beg + wv * 2;
    for (; i + 1 < end; i += 8) {
        const unsigned char* p0 = kv8 + (size_t)ssrc[i] * 1024 + ln * 8;
        const unsigned char* p1 = kv8 + (size_t)ssrc[i + 1] * 1024 + ln * 8;
        uint2 kd0 = *(const uint2*)p0;
        uint2 kd1 = *(const uint2*)p1;
        float2v a0 = {0, 0}, a1 = {0, 0};
        float2v p;
        p = __builtin_amdgcn_cvt_pk_f32_fp8(kd0.x, false); a0 += qf2[0] * p;
        p = __builtin_amdgcn_cvt_pk_f32_fp8(kd0.x, true);  a0 += qf2[1] * p;
        p = __builtin_amdgcn_cvt_pk_f32_fp8(kd0.y, false); a0 += qf2[2] * p;
        p = __builtin_amdgcn_cvt_pk_f32_fp8(kd0.y, true);  a0 += qf2[3] * p;
        p = __builtin_amdgcn_cvt_pk_f32_fp8(kd1.x, false); a1 += qf2[0] * p;
        p = __builtin_amdgcn_cvt_pk_f32_fp8(kd1.x, true);  a1 += qf2[1] * p;
        p = __builtin_amdgcn_cvt_pk_f32_fp8(kd1.y, false); a1 += qf2[2] * p;
        p = __builtin_amdgcn_cvt_pk_f32_fp8(kd1.y, true);  a1 += qf2[3] * p;
        float d0 = a0.x + a0.y, d1 = a1.x + a1.y;
#pragma unroll
        for (int off = 32; off >= 1; off >>= 1) {
            d0 += __shfl_xor(d0, off, 64);
            d1 += __shfl_xor(d1, off, 64);
        }
        float w0 = __expf(d0), w1 = __expf(d1);
        den += w0 + w1;
        uint2 vd0 = *(const uint2*)(p0 + 512);
        uint2 vd1 = *(const uint2*)(p1 + 512);
        float2v w20 = {w0, w0}, w21 = {w1, w1};
        p = __builtin_amdgcn_cvt_pk_f32_fp8(vd0.x, false); av2[0] += w20 * p;
        p = __builtin_amdgcn_cvt_pk_f32_fp8(vd0.x, true);  av2[1] += w20 * p;
        p = __builtin_amdgcn_cvt_pk_f32_fp8(vd0.y, false); av2[2] += w20 * p;
        p = __builtin_amdgcn_cvt_pk_f32_fp8(vd0.y, true);  av2[3] += w20 * p;
        p = __builtin_amdgcn_cvt_pk_f32_fp8(vd1.x, false); av2[0] += w21 * p;
        p = __builtin_amdgcn_cvt_pk_f32_fp8(vd1.x, true);  av2[1] += w21 * p;
        p = __builtin_amdgcn_cvt_pk_f32_fp8(vd1.y, false); av2[2] += w21 * p;
        p = __builtin_amdgcn_cvt_pk_f32_fp8(vd1.y, true);  av2[3] += w21 * p;
    }
    if (i < end) {
        const unsigned char* p0 = kv8 + (size_t)ssrc[i] * 1024 + ln * 8;
        uint2 kd0 = *(const uint2*)p0;
        float2v a0 = {0, 0};
        float2v p;
        p = __builtin_amdgcn_cvt_pk_f32_fp8(kd0.x, false); a0 += qf2[0] * p;
        p = __builtin_amdgcn_cvt_pk_f32_fp8(kd0.x, true);  a0 += qf2[1] * p;
        p = __builtin_amdgcn_cvt_pk_f32_fp8(kd0.y, false); a0 += qf2[2] * p;
        p = __builtin_amdgcn_cvt_pk_f32_fp8(kd0.y, true);  a0 += qf2[3] * p;
        float d0 = a0.x + a0.y;
#pragma unroll
        for (int off = 32; off >= 1; off >>= 1) d0 += __shfl_xor(d0, off, 64);
        float w0 = __expf(d0);
        den += w0;
        uint2 vd0 = *(const uint2*)(p0 + 512);
        float2v w20 = {w0, w0};
        p = __builtin_amdgcn_cvt_pk_f32_fp8(vd0.x, false); av2[0] += w20 * p;
        p = __builtin_amdgcn_cvt_pk_f32_fp8(vd0.x, true);  av2[1] += w20 * p;
        p = __builtin_amdgcn_cvt_pk_f32_fp8(vd0.y, false); av2[2] += w20 * p;
        p = __builtin_amdgcn_cvt_pk_f32_fp8(vd0.y, true);  av2[3] += w20 * p;
    }
    floatx4 s0v = {av2[0].x, av2[0].y, av2[1].x, av2[1].y};
    floatx4 s1v = {av2[2].x, av2[2].y, av2[3].x, av2[3].y};
    *(floatx4*)&sacc[wv][ln * 8]     = s0v;
    *(floatx4*)&sacc[wv][ln * 8 + 4] = s1v;
    if (ln == 0) sden[wv] = den;
    __syncthreads();
    // 0.0625 undoes the x16 fold on v
    float inv = 0.0625f / (sden[0] + sden[1] + sden[2] + sden[3]);
    int c = tid * 2;
    float t0 = sacc[0][c] + sacc[1][c] + sacc[2][c] + sacc[3][c];
    float t1 = sacc[0][c + 1] + sacc[1][c + 1] + sacc[2][c + 1] + sacc[3][c + 1];
    attn[(size_t)n * 512 + c]     = f2bf(t0 * inv);
    attn[(size_t)n * 512 + c + 1] = f2bf(t1 * inv);
}

// ---------------- expmap0 in place --------------------------------------------
__global__ __launch_bounds__(64) void k_expmap(float* h) {
    int row = blockIdx.x, lane = threadIdx.x;
    floatx4* hp = (floatx4*)(h + (size_t)row * DIMK + lane * 8);
    floatx4 h0 = hp[0], h1 = hp[1];
    float ss = 0.f;
#pragma unroll
    for (int i = 0; i < 4; i++) { ss += h0[i] * h0[i]; ss += h1[i] * h1[i]; }
#pragma unroll
    for (int off = 32; off >= 1; off >>= 1) ss += __shfl_xor(ss, off, 64);
    float n  = sqrtf(ss);
    float nc = fmaxf(n, 1e-7f);
    float fac = tanhf(nc) / nc;
#pragma unroll
    for (int i = 0; i < 4; i++) { h0[i] *= fac; h1[i] *= fac; }
    hp[0] = h0; hp[1] = h1;
}

extern "C" void kernel_launch(void* const* d_in, const int* in_sizes, int n_in,
                              void* d_out, int out_size, void* d_ws, size_t ws_size,
                              hipStream_t stream) {
    const float* x  = (const float*)d_in[0];
    const int* src  = (const int*)d_in[1];
    const int* dst  = (const int*)d_in[2];
    const float* Wq = (const float*)d_in[3];
    const float* bq = (const float*)d_in[4];
    const float* Wk = (const float*)d_in[5];
    const float* bk = (const float*)d_in[6];
    const float* Wv = (const float*)d_in[7];
    const float* bv = (const float*)d_in[8];
    const float* Wo = (const float*)d_in[9];
    const float* bo = (const float*)d_in[10];
    float* out = (float*)d_out;

    char* ws = (char*)d_ws;
    const size_t RB = (size_t)NND * DIMK * 2;      // 20.48 MB bf16 [N,512]
    const size_t KVB = (size_t)NND * 1024;         // 20.48 MB fp8 [N, k|v]
    const size_t WB = (size_t)DIMK * DIMK * 2;
    unsigned short* t    = (unsigned short*)(ws);              // reused as attn
    unsigned short* qb   = (unsigned short*)(ws + RB);
    unsigned char*  kv8  = (unsigned char*)(ws + 2 * RB);
    unsigned short* Wqkv = (unsigned short*)(ws + 2 * RB + KVB);
    unsigned short* Wob  = (unsigned short*)(ws + 2 * RB + KVB + 3 * WB);
    float* biasf         = (float*)(ws + 2 * RB + KVB + 4 * WB);
    char* p = ws + 2 * RB + KVB + 4 * WB + 1536 * 4;
    int* ssrc    = (int*)p;
    int* counts  = ssrc + NE;
    int* offsets = counts + NND;
    int* pos     = offsets + NND + 2;
    unsigned short* attn = t;

    hipMemsetAsync(counts, 0, (size_t)NND * 4, stream);

    const float scale_q = 0.04419417382415922f / 16.0f;   // (1/sqrt(512)) / 16
    k_pre<<<7280, 256, 0, stream>>>(x, Wq, Wk, Wv, Wo, bq, bk, bv, dst, counts,
                                    t, Wqkv, Wob, biasf, scale_q);

    k_scan<<<1, 1024, 0, stream>>>(counts, offsets, pos);
    k_scatter<<<(NE + 255) / 256, 256, 0, stream>>>(dst, src, pos, ssrc);

    // fused q/k/v GEMM: [20000 x 1536] -> qb bf16 / kv8 fp8 (k|v interleaved)
    k_gemm<<<8 * 20 * 12, 256, 0, stream>>>(t, Wqkv, biasf, qb, kv8, nullptr,
                                            NND, 157, 12, 1536);

    k_fsa<<<NND, 256, 0, stream>>>(offsets, ssrc, qb, kv8, attn);

    // output projection (fp32 into d_out), expmap in place
    k_gemm<<<8 * 20 * 4, 256, 0, stream>>>(attn, Wob, bo, nullptr, nullptr, out,
                                           NND, 157, 4, 512);
    k_expmap<<<NND, 64, 0, stream>>>(out);
}